// Round 1
// baseline (3379.652 us; speedup 1.0000x reference)
//
#include <hip/hip_runtime.h>
#include <math.h>

#define NTOK 2025
#define NBS  4050   // NTOK * BS
#define BSZ  2

__device__ __forceinline__ float silu_f(float v){ return v / (1.f + __expf(-v)); }

// ---------------- LayerNorm over C=256 ----------------
__global__ __launch_bounds__(256) void ln256_kernel(
    const float* __restrict__ in, const float* __restrict__ g,
    const float* __restrict__ bta, float* __restrict__ out,
    int ldout, int col0)
{
  int row = blockIdx.x;
  int t = threadIdx.x;
  float x = in[(size_t)row*256 + t];
  float s = x, s2 = x*x;
  #pragma unroll
  for (int o=32; o>0; o>>=1){ s += __shfl_xor(s,o); s2 += __shfl_xor(s2,o); }
  __shared__ float w1[4], w2[4];
  __shared__ float mean_s, rstd_s;
  int wid = t>>6, lane = t&63;
  if (lane==0){ w1[wid]=s; w2[wid]=s2; }
  __syncthreads();
  if (t==0){
    float S  = w1[0]+w1[1]+w1[2]+w1[3];
    float S2 = w2[0]+w2[1]+w2[2]+w2[3];
    float m = S*(1.f/256.f);
    float v = S2*(1.f/256.f) - m*m;
    mean_s = m; rstd_s = rsqrtf(v + 1e-5f);
  }
  __syncthreads();
  out[(size_t)row*ldout + col0 + t] = (x-mean_s)*rstd_s*g[t] + bta[t];
}

// ---------------- fp32 GEMM: C = A(MxK) @ B(KxN) + bias, EPI: 0 none 1 silu; ACC adds into C
template<int EPI, int ACC>
__global__ __launch_bounds__(256) void gemm64_kernel(
    const float* __restrict__ A, int lda,
    const float* __restrict__ B, int ldb,
    const float* __restrict__ bias,
    float* __restrict__ C, int ldc, int col0,
    int M, int K)
{
  __shared__ float As[16][64];
  __shared__ float Bs[16][64];
  const int m0 = blockIdx.x*64, n0 = blockIdx.y*64;
  const int t = threadIdx.x;
  const int ty = t>>4, tx = t&15;
  const int ar = t>>2, ak = (t&3)<<2;
  const int bk = t>>4, bc = (t&15)<<2;
  float acc[4][4] = {};
  for (int k0=0; k0<K; k0+=16){
    float4 a = make_float4(0.f,0.f,0.f,0.f);
    if (m0+ar < M) a = *reinterpret_cast<const float4*>(A + (size_t)(m0+ar)*lda + k0 + ak);
    As[ak+0][ar]=a.x; As[ak+1][ar]=a.y; As[ak+2][ar]=a.z; As[ak+3][ar]=a.w;
    float4 bv = *reinterpret_cast<const float4*>(B + (size_t)(k0+bk)*ldb + n0 + bc);
    *reinterpret_cast<float4*>(&Bs[bk][bc]) = bv;
    __syncthreads();
    #pragma unroll
    for (int k=0;k<16;k++){
      float4 a4 = *reinterpret_cast<const float4*>(&As[k][ty<<2]);
      float4 b4 = *reinterpret_cast<const float4*>(&Bs[k][tx<<2]);
      float av[4] = {a4.x,a4.y,a4.z,a4.w};
      float bw[4] = {b4.x,b4.y,b4.z,b4.w};
      #pragma unroll
      for (int i=0;i<4;i++)
        #pragma unroll
        for (int j=0;j<4;j++) acc[i][j] += av[i]*bw[j];
    }
    __syncthreads();
  }
  #pragma unroll
  for (int i=0;i<4;i++){
    int row = m0 + (ty<<2) + i;
    if (row >= M) break;
    #pragma unroll
    for (int j=0;j<4;j++){
      int col = n0 + (tx<<2) + j;
      float v = acc[i][j] + bias[col];
      if (ACC) v += C[(size_t)row*ldc + col0 + col];
      if (EPI==1) v = silu_f(v);
      C[(size_t)row*ldc + col0 + col] = v;
    }
  }
}

// ---------------- flash attention: per (b,h), 32-query tile, DA=32, dv=128
// Q,K layout: (n*2+b)*256 + h*32 + d ; V layout: (n*2+b)*1024 + h*128 + e
// Out gated: Out[(n*2+b)*1024 + h*128+e] = O*inv_l * (ch<gateW ? Ug[row*gateW+ch] : 1)
__global__ __launch_bounds__(256) void flash_attn_kernel(
    const float* __restrict__ Qp, const float* __restrict__ Kp,
    const float* __restrict__ Vp, const float* __restrict__ Ug,
    float* __restrict__ Out, int gateW)
{
  __shared__ float qs[32][32];
  __shared__ float ks[32][32];
  __shared__ float ss[32][33];
  __shared__ float4 vs[32][32];
  __shared__ float mL[32], lL[32], aL[32];
  const int t = threadIdx.x;
  const int h = blockIdx.y, b = blockIdx.z;
  const int r0 = blockIdx.x * 32;
  const float scale = 0.17677669529663687f; // 1/sqrt(32)

  { // load Q tile, scaled
    int r = t>>3, d4 = (t&7)<<2;
    int n = r0 + r;
    float4 q = make_float4(0,0,0,0);
    if (n < NTOK) q = *reinterpret_cast<const float4*>(Qp + (size_t)(n*2+b)*256 + h*32 + d4);
    qs[r][d4+0]=q.x*scale; qs[r][d4+1]=q.y*scale; qs[r][d4+2]=q.z*scale; qs[r][d4+3]=q.w*scale;
  }
  if (t < 32){ mL[t] = -1e30f; lL[t] = 0.f; }
  float acc[16];
  #pragma unroll
  for (int j=0;j<16;j++) acc[j]=0.f;
  const int rq = t & 31;
  const int eb = t >> 5;          // 0..7
  const int cb = eb << 2;         // score col base
  __syncthreads();
  float qreg[32];
  #pragma unroll
  for (int d=0; d<32; d++) qreg[d] = qs[rq][d];

  for (int kt=0; kt<64; kt++){
    int k0 = kt*32;
    { // K tile
      int r=t>>3, d4=(t&7)<<2; int n=k0+r;
      float4 kv = make_float4(0,0,0,0);
      if (n < NTOK) kv = *reinterpret_cast<const float4*>(Kp + (size_t)(n*2+b)*256 + h*32 + d4);
      ks[r][d4+0]=kv.x; ks[r][d4+1]=kv.y; ks[r][d4+2]=kv.z; ks[r][d4+3]=kv.w;
    }
    #pragma unroll
    for (int i=0;i<4;i++){ // V tile: 32 keys x 32 float4
      int idx = t + i*256;
      int k = idx>>5, e4 = idx&31;
      int n = k0+k;
      vs[k][e4] = (n < NTOK) ? *reinterpret_cast<const float4*>(Vp + (size_t)(n*2+b)*1024 + h*128 + (e4<<2))
                             : make_float4(0,0,0,0);
    }
    __syncthreads();
    #pragma unroll
    for (int cc=0; cc<4; cc++){
      int ck = cb+cc;
      const float4* krow = reinterpret_cast<const float4*>(&ks[ck][0]);
      float s = 0.f;
      #pragma unroll
      for (int d4=0; d4<8; d4++){
        float4 kv = krow[d4];
        s += qreg[d4*4+0]*kv.x + qreg[d4*4+1]*kv.y + qreg[d4*4+2]*kv.z + qreg[d4*4+3]*kv.w;
      }
      ss[rq][ck] = (k0+ck < NTOK) ? s : -1e30f;
    }
    __syncthreads();
    if (t < 32){
      int r = t;
      float m0 = mL[r];
      float tm = -1e30f;
      for (int k=0;k<32;k++) tm = fmaxf(tm, ss[r][k]);
      float nm = fmaxf(m0, tm);
      float al = __expf(m0 - nm);
      float sum = 0.f;
      for (int k=0;k<32;k++){ float p = __expf(ss[r][k]-nm); ss[r][k]=p; sum+=p; }
      lL[r] = lL[r]*al + sum;
      mL[r] = nm; aL[r] = al;
    }
    __syncthreads();
    float al = aL[rq];
    #pragma unroll
    for (int j=0;j<16;j++) acc[j]*=al;
    for (int ck=0; ck<32; ck++){
      float p = ss[rq][ck];
      #pragma unroll
      for (int j4=0;j4<4;j4++){
        float4 v = vs[ck][(eb<<2)+j4];
        acc[j4*4+0] += p*v.x; acc[j4*4+1] += p*v.y; acc[j4*4+2] += p*v.z; acc[j4*4+3] += p*v.w;
      }
    }
    __syncthreads();
  }
  int n = r0+rq;
  if (n < NTOK){
    float linv = 1.f / lL[rq];
    size_t rb = (size_t)(n*2+b);
    #pragma unroll
    for (int j=0;j<16;j++){
      int ch = h*128 + (eb<<4) + j;
      float g = (ch < gateW) ? Ug[rb*gateW + ch] : 1.f;
      Out[rb*1024 + ch] = acc[j]*linv*g;
    }
  }
}

// ---------------- local windowed attention (15x15), one block per (b,h,y)
__global__ __launch_bounds__(256) void local_attn_kernel(
    const float* __restrict__ Qp, const float* __restrict__ Vp, const float* __restrict__ Ug,
    const float* __restrict__ Wrel, const float* __restrict__ brel, float* __restrict__ Out)
{
  __shared__ float qrow[45][32];
  __shared__ float sc[45][225];
  const int t = threadIdx.x;
  const int y = blockIdx.x, h = blockIdx.y, b = blockIdx.z;
  const float scale = 0.17677669529663687f;

  for (int idx=t; idx<45*32; idx+=256){
    int px = idx>>5, d = idx&31;
    int n = y*45 + px;
    qrow[px][d] = Qp[(size_t)(n*2+b)*256 + h*32 + d] * scale;
  }
  __syncthreads();
  for (int idx=t; idx<45*225; idx+=256){
    int px = idx/225, o = idx - px*225;
    int dy = o/15 - 7, dx = o%15 - 7;
    int yy = y+dy, xx = px+dx;
    float s;
    if (yy>=0 && yy<45 && xx>=0 && xx<45){
      int nk = yy*45+xx;
      const float4* kp4 = reinterpret_cast<const float4*>(Qp + (size_t)(nk*2+b)*256 + h*32);
      const float4* wr4 = reinterpret_cast<const float4*>(Wrel + ((size_t)h*225 + o)*32);
      float dot=0.f, rel=0.f;
      #pragma unroll
      for (int d4=0; d4<8; d4++){
        float4 kv = kp4[d4]; float4 wv = wr4[d4];
        float q0=qrow[px][d4*4+0], q1=qrow[px][d4*4+1], q2=qrow[px][d4*4+2], q3=qrow[px][d4*4+3];
        dot += q0*kv.x + q1*kv.y + q2*kv.z + q3*kv.w;
        rel += q0*wv.x + q1*wv.y + q2*wv.z + q3*wv.w;
      }
      s = dot + rel + brel[h*225+o];
    } else s = -1e9f;
    sc[px][o] = s;
  }
  __syncthreads();
  for (int px=t; px<45; px+=256){
    float m = -1e30f;
    for (int o=0;o<225;o++) m = fmaxf(m, sc[px][o]);
    float sum = 0.f;
    for (int o=0;o<225;o++){ float p = __expf(sc[px][o]-m); sc[px][o]=p; sum+=p; }
    float inv = 1.f/sum;
    for (int o=0;o<225;o++) sc[px][o] *= inv;
  }
  __syncthreads();
  for (int idx=t; idx<45*128; idx+=256){
    int px = idx>>7, e = idx&127;
    float accv = 0.f;
    for (int o=0;o<225;o++){
      int dy = o/15 - 7, dx = o%15 - 7;
      int yy = y+dy, xx = px+dx;
      if (yy>=0 && yy<45 && xx>=0 && xx<45){
        accv += sc[px][o] * Vp[(size_t)((yy*45+xx)*2+b)*1024 + h*128 + e];
      }
    }
    int n = y*45+px;
    int ch = h*128+e;
    size_t rb = (size_t)(n*2+b);
    float g = (ch < 512) ? Ug[rb*512 + ch] : 1.f;
    Out[rb*1024 + ch] = accv*g;
  }
}

// ---------------- residual split: new_tgt = tgt + t23[:, :256]; tgt_id = t23[:, 256:]
__global__ __launch_bounds__(256) void resid_split_kernel(
    const float* __restrict__ tgt, const float* __restrict__ t23,
    float* __restrict__ newt, float* __restrict__ tgtid)
{
  int idx = blockIdx.x*256 + threadIdx.x;
  if (idx >= NBS*256) return;
  int row = idx >> 8, c = idx & 255;
  newt[idx]  = tgt[idx] + t23[(size_t)row*512 + c];
  tgtid[idx] = t23[(size_t)row*512 + 256 + c];
}

// ---------------- final: out0 = newt + s2[:, :256]; out1 = tgtid + s2[:, 256:]
__global__ __launch_bounds__(256) void final_add_kernel(
    const float* __restrict__ newt, const float* __restrict__ tgtid,
    const float* __restrict__ s2, float* __restrict__ out)
{
  int idx = blockIdx.x*256 + threadIdx.x;
  if (idx >= NBS*256) return;
  int row = idx >> 8, c = idx & 255;
  out[idx]            = newt[idx]  + s2[(size_t)row*512 + c];
  out[NBS*256 + idx]  = tgtid[idx] + s2[(size_t)row*512 + 256 + c];
}

extern "C" void kernel_launch(void* const* d_in, const int* in_sizes, int n_in,
                              void* d_out, int out_size, void* d_ws, size_t ws_size,
                              hipStream_t stream)
{
  const float* tgt    = (const float*)d_in[0];
  const float* id_emb = (const float*)d_in[1];
  const float* ln1_g  = (const float*)d_in[2];
  const float* ln1_b  = (const float*)d_in[3];
  const float* W_qv   = (const float*)d_in[4];
  const float* b_qv   = (const float*)d_in[5];
  const float* W_u    = (const float*)d_in[6];
  const float* b_u    = (const float*)d_in[7];
  const float* W_idv  = (const float*)d_in[8];
  const float* b_idv  = (const float*)d_in[9];
  const float* lt_Wo  = (const float*)d_in[10];
  const float* lt_bo  = (const float*)d_in[11];
  const float* Wrel   = (const float*)d_in[12];
  const float* brel   = (const float*)d_in[13];
  const float* st_Wo  = (const float*)d_in[14];
  const float* st_bo  = (const float*)d_in[15];
  const float* ln2_g  = (const float*)d_in[16];
  const float* ln2_b  = (const float*)d_in[17];
  const float* idln2_g= (const float*)d_in[18];
  const float* idln2_b= (const float*)d_in[19];
  const float* sa_Wqk = (const float*)d_in[20];
  const float* sa_bqk = (const float*)d_in[21];
  const float* sa_Wv  = (const float*)d_in[22];
  const float* sa_bv  = (const float*)d_in[23];
  const float* sa_Wu  = (const float*)d_in[24];
  const float* sa_bu  = (const float*)d_in[25];
  const float* sa_Wo  = (const float*)d_in[26];
  const float* sa_bo  = (const float*)d_in[27];
  float* out = (float*)d_out;
  float* ws  = (float*)d_ws;

  // workspace layout (floats); total 19,699,200 floats = 78.8 MB
  float* tgt_ln = ws;                 // 1,036,800  (reused as newt)
  float* Qbuf   = ws + 1036800;       // 1,036,800  (reused as Qs)
  float* Vbuf   = ws + 2073600;       // 4,147,200  (reused as Vs)
  float* Ubuf   = ws + 6220800;       // 2,073,600  (reused as s2)
  float* G1     = ws + 8294400;       // 4,147,200  (attn1 gated out; reused attn2)
  float* G2     = ws + 12441600;      // 4,147,200  (local gated out; reused as Us)
  float* t23    = ws + 16588800;      // 2,073,600  (reused as x)
  float* tgtid  = ws + 18662400;      // 1,036,800
  const int M = NBS;
  dim3 blk(256);
  int gx = (M+63)/64;

  // LN1
  ln256_kernel<<<M, 256, 0, stream>>>(tgt, ln1_g, ln1_b, tgt_ln, 256, 0);

  // qv = _tgt @ W_qv : cols [0,256)->Q raw, [256,768)->silu->V[:, :512]
  gemm64_kernel<0,0><<<dim3(gx, 4), blk, 0, stream>>>(tgt_ln,256, W_qv,    768, b_qv,     Qbuf,256,  0,   M,256);
  gemm64_kernel<1,0><<<dim3(gx, 8), blk, 0, stream>>>(tgt_ln,256, W_qv+256,768, b_qv+256, Vbuf,1024, 0,   M,256);
  // silu(curr_U)
  gemm64_kernel<1,0><<<dim3(gx, 8), blk, 0, stream>>>(tgt_ln,256, W_u,     512, b_u,      Ubuf,512,  0,   M,256);
  // g_ID_V = silu(id_emb @ W_idv) -> V[:, 512:]
  gemm64_kernel<1,0><<<dim3(gx, 8), blk, 0, stream>>>(id_emb,256, W_idv,   512, b_idv,    Vbuf,1024, 512, M,256);

  // global attn 1 (gate width 512) and local attn
  flash_attn_kernel<<<dim3(64,8,2), blk, 0, stream>>>(Qbuf, Qbuf, Vbuf, Ubuf, G1, 512);
  local_attn_kernel<<<dim3(45,8,2), blk, 0, stream>>>(Qbuf, Vbuf, Ubuf, Wrel, brel, G2);

  // t23 = G1 @ lt_Wo + lt_bo + G2 @ st_Wo + st_bo
  gemm64_kernel<0,0><<<dim3(gx, 8), blk, 0, stream>>>(G1,1024, lt_Wo,512, lt_bo, t23,512,0, M,1024);
  gemm64_kernel<0,1><<<dim3(gx, 8), blk, 0, stream>>>(G2,1024, st_Wo,512, st_bo, t23,512,0, M,1024);

  // residuals
  float* newt = tgt_ln;
  resid_split_kernel<<<(M*256+255)/256, blk, 0, stream>>>(tgt, t23, newt, tgtid);

  // x = [ln(newt), ln(tgtid)]
  float* xbuf = t23;
  ln256_kernel<<<M, 256, 0, stream>>>(newt,  ln2_g,   ln2_b,   xbuf, 512, 0);
  ln256_kernel<<<M, 256, 0, stream>>>(tgtid, idln2_g, idln2_b, xbuf, 512, 256);

  // Qs / Vs / Us
  float* Qs = Qbuf; float* Vs = Vbuf; float* Us = G2;
  gemm64_kernel<0,0><<<dim3(gx, 4),  blk, 0, stream>>>(xbuf,512, sa_Wqk,256,  sa_bqk, Qs,256,  0, M,512);
  gemm64_kernel<1,0><<<dim3(gx, 16), blk, 0, stream>>>(xbuf,512, sa_Wv,1024,  sa_bv,  Vs,1024, 0, M,512);
  gemm64_kernel<1,0><<<dim3(gx, 16), blk, 0, stream>>>(xbuf,512, sa_Wu,1024,  sa_bu,  Us,1024, 0, M,512);

  // global attn 2 (gate width 1024)
  flash_attn_kernel<<<dim3(64,8,2), blk, 0, stream>>>(Qs, Qs, Vs, Us, G1, 1024);

  // s2 = gated @ sa_Wo + sa_bo
  float* s2 = Ubuf;
  gemm64_kernel<0,0><<<dim3(gx, 8), blk, 0, stream>>>(G1,1024, sa_Wo,512, sa_bo, s2,512,0, M,1024);

  final_add_kernel<<<(M*256+255)/256, blk, 0, stream>>>(newt, tgtid, s2, out);
}

// Round 2
// 2174.204 us; speedup vs baseline: 1.5544x; 1.5544x over previous
//
#include <hip/hip_runtime.h>
#include <math.h>

#define NTOK 2025
#define NBS  4050   // NTOK * BS
#define BSZ  2

__device__ __forceinline__ float silu_f(float v){ return v / (1.f + __expf(-v)); }

// ---------------- LayerNorm over C=256 ----------------
__global__ __launch_bounds__(256) void ln256_kernel(
    const float* __restrict__ in, const float* __restrict__ g,
    const float* __restrict__ bta, float* __restrict__ out,
    int ldout, int col0)
{
  int row = blockIdx.x;
  int t = threadIdx.x;
  float x = in[(size_t)row*256 + t];
  float s = x, s2 = x*x;
  #pragma unroll
  for (int o=32; o>0; o>>=1){ s += __shfl_xor(s,o); s2 += __shfl_xor(s2,o); }
  __shared__ float w1[4], w2[4];
  __shared__ float mean_s, rstd_s;
  int wid = t>>6, lane = t&63;
  if (lane==0){ w1[wid]=s; w2[wid]=s2; }
  __syncthreads();
  if (t==0){
    float S  = w1[0]+w1[1]+w1[2]+w1[3];
    float S2 = w2[0]+w2[1]+w2[2]+w2[3];
    float m = S*(1.f/256.f);
    float v = S2*(1.f/256.f) - m*m;
    mean_s = m; rstd_s = rsqrtf(v + 1e-5f);
  }
  __syncthreads();
  out[(size_t)row*ldout + col0 + t] = (x-mean_s)*rstd_s*g[t] + bta[t];
}

// ---------------- fp32 GEMM: C = A(MxK) @ B(KxN) + bias, EPI: 0 none 1 silu; ACC adds into C
template<int EPI, int ACC>
__global__ __launch_bounds__(256) void gemm64_kernel(
    const float* __restrict__ A, int lda,
    const float* __restrict__ B, int ldb,
    const float* __restrict__ bias,
    float* __restrict__ C, int ldc, int col0,
    int M, int K)
{
  __shared__ float As[16][64];
  __shared__ float Bs[16][64];
  const int m0 = blockIdx.x*64, n0 = blockIdx.y*64;
  const int t = threadIdx.x;
  const int ty = t>>4, tx = t&15;
  const int ar = t>>2, ak = (t&3)<<2;
  const int bk = t>>4, bc = (t&15)<<2;
  float acc[4][4] = {};
  for (int k0=0; k0<K; k0+=16){
    float4 a = make_float4(0.f,0.f,0.f,0.f);
    if (m0+ar < M) a = *reinterpret_cast<const float4*>(A + (size_t)(m0+ar)*lda + k0 + ak);
    As[ak+0][ar]=a.x; As[ak+1][ar]=a.y; As[ak+2][ar]=a.z; As[ak+3][ar]=a.w;
    float4 bv = *reinterpret_cast<const float4*>(B + (size_t)(k0+bk)*ldb + n0 + bc);
    *reinterpret_cast<float4*>(&Bs[bk][bc]) = bv;
    __syncthreads();
    #pragma unroll
    for (int k=0;k<16;k++){
      float4 a4 = *reinterpret_cast<const float4*>(&As[k][ty<<2]);
      float4 b4 = *reinterpret_cast<const float4*>(&Bs[k][tx<<2]);
      float av[4] = {a4.x,a4.y,a4.z,a4.w};
      float bw[4] = {b4.x,b4.y,b4.z,b4.w};
      #pragma unroll
      for (int i=0;i<4;i++)
        #pragma unroll
        for (int j=0;j<4;j++) acc[i][j] += av[i]*bw[j];
    }
    __syncthreads();
  }
  #pragma unroll
  for (int i=0;i<4;i++){
    int row = m0 + (ty<<2) + i;
    if (row >= M) break;
    #pragma unroll
    for (int j=0;j<4;j++){
      int col = n0 + (tx<<2) + j;
      float v = acc[i][j] + bias[col];
      if (ACC) v += C[(size_t)row*ldc + col0 + col];
      if (EPI==1) v = silu_f(v);
      C[(size_t)row*ldc + col0 + col] = v;
    }
  }
}

// ---------------- flash attention: per (b,h), 32-query tile, DA=32, dv=128
__global__ __launch_bounds__(256) void flash_attn_kernel(
    const float* __restrict__ Qp, const float* __restrict__ Kp,
    const float* __restrict__ Vp, const float* __restrict__ Ug,
    float* __restrict__ Out, int gateW)
{
  __shared__ float qs[32][32];
  __shared__ float ks[32][32];
  __shared__ float ss[32][33];
  __shared__ float4 vs[32][32];
  __shared__ float mL[32], lL[32], aL[32];
  const int t = threadIdx.x;
  const int h = blockIdx.y, b = blockIdx.z;
  const int r0 = blockIdx.x * 32;
  const float scale = 0.17677669529663687f; // 1/sqrt(32)

  { // load Q tile, scaled
    int r = t>>3, d4 = (t&7)<<2;
    int n = r0 + r;
    float4 q = make_float4(0,0,0,0);
    if (n < NTOK) q = *reinterpret_cast<const float4*>(Qp + (size_t)(n*2+b)*256 + h*32 + d4);
    qs[r][d4+0]=q.x*scale; qs[r][d4+1]=q.y*scale; qs[r][d4+2]=q.z*scale; qs[r][d4+3]=q.w*scale;
  }
  if (t < 32){ mL[t] = -1e30f; lL[t] = 0.f; }
  float acc[16];
  #pragma unroll
  for (int j=0;j<16;j++) acc[j]=0.f;
  const int rq = t & 31;
  const int eb = t >> 5;          // 0..7
  const int cb = eb << 2;         // score col base
  __syncthreads();
  float qreg[32];
  #pragma unroll
  for (int d=0; d<32; d++) qreg[d] = qs[rq][d];

  for (int kt=0; kt<64; kt++){
    int k0 = kt*32;
    { // K tile
      int r=t>>3, d4=(t&7)<<2; int n=k0+r;
      float4 kv = make_float4(0,0,0,0);
      if (n < NTOK) kv = *reinterpret_cast<const float4*>(Kp + (size_t)(n*2+b)*256 + h*32 + d4);
      ks[r][d4+0]=kv.x; ks[r][d4+1]=kv.y; ks[r][d4+2]=kv.z; ks[r][d4+3]=kv.w;
    }
    #pragma unroll
    for (int i=0;i<4;i++){ // V tile: 32 keys x 32 float4
      int idx = t + i*256;
      int k = idx>>5, e4 = idx&31;
      int n = k0+k;
      vs[k][e4] = (n < NTOK) ? *reinterpret_cast<const float4*>(Vp + (size_t)(n*2+b)*1024 + h*128 + (e4<<2))
                             : make_float4(0,0,0,0);
    }
    __syncthreads();
    #pragma unroll
    for (int cc=0; cc<4; cc++){
      int ck = cb+cc;
      const float4* krow = reinterpret_cast<const float4*>(&ks[ck][0]);
      float s = 0.f;
      #pragma unroll
      for (int d4=0; d4<8; d4++){
        float4 kv = krow[d4];
        s += qreg[d4*4+0]*kv.x + qreg[d4*4+1]*kv.y + qreg[d4*4+2]*kv.z + qreg[d4*4+3]*kv.w;
      }
      ss[rq][ck] = (k0+ck < NTOK) ? s : -1e30f;
    }
    __syncthreads();
    if (t < 32){
      int r = t;
      float m0 = mL[r];
      float tm = -1e30f;
      for (int k=0;k<32;k++) tm = fmaxf(tm, ss[r][k]);
      float nm = fmaxf(m0, tm);
      float al = __expf(m0 - nm);
      float sum = 0.f;
      for (int k=0;k<32;k++){ float p = __expf(ss[r][k]-nm); ss[r][k]=p; sum+=p; }
      lL[r] = lL[r]*al + sum;
      mL[r] = nm; aL[r] = al;
    }
    __syncthreads();
    float al = aL[rq];
    #pragma unroll
    for (int j=0;j<16;j++) acc[j]*=al;
    for (int ck=0; ck<32; ck++){
      float p = ss[rq][ck];
      #pragma unroll
      for (int j4=0;j4<4;j4++){
        float4 v = vs[ck][(eb<<2)+j4];
        acc[j4*4+0] += p*v.x; acc[j4*4+1] += p*v.y; acc[j4*4+2] += p*v.z; acc[j4*4+3] += p*v.w;
      }
    }
    __syncthreads();
  }
  int n = r0+rq;
  if (n < NTOK){
    float linv = 1.f / lL[rq];
    size_t rb = (size_t)(n*2+b);
    #pragma unroll
    for (int j=0;j<16;j++){
      int ch = h*128 + (eb<<4) + j;
      float g = (ch < gateW) ? Ug[rb*gateW + ch] : 1.f;
      Out[rb*1024 + ch] = acc[j]*linv*g;
    }
  }
}

// ---------------- local windowed attention (15x15), one block per (b,h,y)
// LDS-staged rewrite: K/Wrel staged per-dy for scores, V staged per-dy for aggregation,
// wave-parallel softmax. qs 5.76KB + sc 39.6KB + buf 30.2KB = ~76.5KB -> 2 blocks/CU.
__global__ __launch_bounds__(256) void local_attn_kernel(
    const float* __restrict__ Qp, const float* __restrict__ Vp, const float* __restrict__ Ug,
    const float* __restrict__ Wrel, const float* __restrict__ brel_g, float* __restrict__ Out)
{
  __shared__ float qs[45][32];
  __shared__ float sc[45][225];
  __shared__ float buf[59*128];   // phase A: ks[59][32], wr[15][32], brs[15]; phase C: vsm[59][128]
  const int t = threadIdx.x;
  const int y = blockIdx.x, h = blockIdx.y, b = blockIdx.z;
  const float scale = 0.17677669529663687f;

  // load Q row (45x32), scaled
  for (int idx=t; idx<45*8; idx+=256){
    int px = idx>>3, d4 = (idx&7)<<2;
    int n = y*45 + px;
    float4 q = *reinterpret_cast<const float4*>(Qp + (size_t)(n*2+b)*256 + h*32 + d4);
    qs[px][d4+0]=q.x*scale; qs[px][d4+1]=q.y*scale; qs[px][d4+2]=q.z*scale; qs[px][d4+3]=q.w*scale;
  }

  float* ks  = buf;                 // [59][32] padded key row
  float* wr  = buf + 59*32;         // [15][32]
  float* brs = buf + 59*32 + 15*32; // [15]

  // ---- phase A: scores ----
  for (int dy=0; dy<15; dy++){
    int yy = y + dy - 7;
    __syncthreads();   // protect buf (and qs on first iter) before overwrite
    if (yy >= 0 && yy < 45){
      for (int idx=t; idx<59*8; idx+=256){
        int xxp = idx>>3, d4 = (idx&7)<<2;
        int xx = xxp - 7;
        float4 kv = make_float4(0,0,0,0);
        if (xx >= 0 && xx < 45)
          kv = *reinterpret_cast<const float4*>(Qp + (size_t)((yy*45+xx)*2+b)*256 + h*32 + d4);
        *reinterpret_cast<float4*>(&ks[xxp*32 + d4]) = kv;
      }
      for (int idx=t; idx<15*8; idx+=256){
        int dx = idx>>3, d4 = (idx&7)<<2;
        *reinterpret_cast<float4*>(&wr[dx*32+d4]) =
          *reinterpret_cast<const float4*>(Wrel + ((size_t)h*225 + dy*15+dx)*32 + d4);
      }
      if (t < 15) brs[t] = brel_g[h*225 + dy*15 + t];
      __syncthreads();
      for (int idx=t; idx<675; idx+=256){
        int px = idx/15, dx = idx - px*15;
        int xx = px + dx - 7;
        float s = -1e9f;
        if (xx >= 0 && xx < 45){
          const float4* q4 = reinterpret_cast<const float4*>(&qs[px][0]);
          const float4* k4 = reinterpret_cast<const float4*>(&ks[(px+dx)*32]);
          const float4* w4 = reinterpret_cast<const float4*>(&wr[dx*32]);
          float acc = 0.f;
          #pragma unroll
          for (int d=0; d<8; d++){
            float4 q = q4[d], kv = k4[d], wv = w4[d];
            acc += q.x*(kv.x+wv.x) + q.y*(kv.y+wv.y) + q.z*(kv.z+wv.z) + q.w*(kv.w+wv.w);
          }
          s = acc + brs[dx];
        }
        sc[px][dy*15+dx] = s;
      }
    } else {
      for (int idx=t; idx<675; idx+=256){
        int px = idx/15, dx = idx - px*15;
        sc[px][dy*15+dx] = -1e9f;
      }
    }
  }
  __syncthreads();

  // ---- phase B: wave-parallel softmax (32-lane group per row) ----
  {
    int grp = t>>5, lane = t&31;
    for (int px = grp; px < 45; px += 8){
      float m = -1e30f;
      for (int o=lane; o<225; o+=32) m = fmaxf(m, sc[px][o]);
      #pragma unroll
      for (int off=16; off>0; off>>=1) m = fmaxf(m, __shfl_xor(m, off));
      float sum = 0.f;
      for (int o=lane; o<225; o+=32){ float p = __expf(sc[px][o]-m); sc[px][o]=p; sum += p; }
      #pragma unroll
      for (int off=16; off>0; off>>=1) sum += __shfl_xor(sum, off);
      float inv = 1.f/sum;
      for (int o=lane; o<225; o+=32) sc[px][o] *= inv;
    }
  }
  __syncthreads();

  // ---- phase C: aggregation, V row staged in LDS ----
  float4 acc[6];
  #pragma unroll
  for (int i=0;i<6;i++) acc[i]=make_float4(0.f,0.f,0.f,0.f);
  float* vsm = buf;   // [59][128]
  for (int dy=0; dy<15; dy++){
    int yy = y + dy - 7;
    if (yy < 0 || yy >= 45) continue;   // block-uniform branch (p==0 there)
    __syncthreads();
    for (int idx=t; idx<59*32; idx+=256){
      int xxp = idx>>5, e4 = (idx&31)<<2;
      int xx = xxp - 7;
      float4 v = make_float4(0.f,0.f,0.f,0.f);
      if (xx>=0 && xx<45)
        v = *reinterpret_cast<const float4*>(Vp + (size_t)((yy*45+xx)*2+b)*1024 + h*128 + e4);
      *reinterpret_cast<float4*>(&vsm[xxp*128 + e4]) = v;
    }
    __syncthreads();
    #pragma unroll
    for (int k=0;k<6;k++){
      int slot = t + 256*k;
      if (slot >= 1440) break;
      int px = slot>>5, e4 = (slot&31)<<2;
      float4 a = acc[k];
      #pragma unroll
      for (int dx=0; dx<15; dx++){
        float p = sc[px][dy*15+dx];
        float4 v = *reinterpret_cast<const float4*>(&vsm[(px+dx)*128 + e4]);
        a.x += p*v.x; a.y += p*v.y; a.z += p*v.z; a.w += p*v.w;
      }
      acc[k] = a;
    }
  }

  // ---- epilogue: gate + store ----
  #pragma unroll
  for (int k=0;k<6;k++){
    int slot = t + 256*k;
    if (slot >= 1440) break;
    int px = slot>>5, e4 = (slot&31)<<2;
    int n = y*45 + px;
    size_t rb = (size_t)(n*2+b);
    int ch = h*128 + e4;
    float4 a = acc[k];
    if (ch < 512){
      float4 g = *reinterpret_cast<const float4*>(Ug + rb*512 + ch);
      a.x *= g.x; a.y *= g.y; a.z *= g.z; a.w *= g.w;
    }
    *reinterpret_cast<float4*>(Out + rb*1024 + ch) = a;
  }
}

// ---------------- residual split: new_tgt = tgt + t23[:, :256]; tgt_id = t23[:, 256:]
__global__ __launch_bounds__(256) void resid_split_kernel(
    const float* __restrict__ tgt, const float* __restrict__ t23,
    float* __restrict__ newt, float* __restrict__ tgtid)
{
  int idx = blockIdx.x*256 + threadIdx.x;
  if (idx >= NBS*256) return;
  int row = idx >> 8, c = idx & 255;
  newt[idx]  = tgt[idx] + t23[(size_t)row*512 + c];
  tgtid[idx] = t23[(size_t)row*512 + 256 + c];
}

// ---------------- final: out0 = newt + s2[:, :256]; out1 = tgtid + s2[:, 256:]
__global__ __launch_bounds__(256) void final_add_kernel(
    const float* __restrict__ newt, const float* __restrict__ tgtid,
    const float* __restrict__ s2, float* __restrict__ out)
{
  int idx = blockIdx.x*256 + threadIdx.x;
  if (idx >= NBS*256) return;
  int row = idx >> 8, c = idx & 255;
  out[idx]            = newt[idx]  + s2[(size_t)row*512 + c];
  out[NBS*256 + idx]  = tgtid[idx] + s2[(size_t)row*512 + 256 + c];
}

extern "C" void kernel_launch(void* const* d_in, const int* in_sizes, int n_in,
                              void* d_out, int out_size, void* d_ws, size_t ws_size,
                              hipStream_t stream)
{
  const float* tgt    = (const float*)d_in[0];
  const float* id_emb = (const float*)d_in[1];
  const float* ln1_g  = (const float*)d_in[2];
  const float* ln1_b  = (const float*)d_in[3];
  const float* W_qv   = (const float*)d_in[4];
  const float* b_qv   = (const float*)d_in[5];
  const float* W_u    = (const float*)d_in[6];
  const float* b_u    = (const float*)d_in[7];
  const float* W_idv  = (const float*)d_in[8];
  const float* b_idv  = (const float*)d_in[9];
  const float* lt_Wo  = (const float*)d_in[10];
  const float* lt_bo  = (const float*)d_in[11];
  const float* Wrel   = (const float*)d_in[12];
  const float* brel   = (const float*)d_in[13];
  const float* st_Wo  = (const float*)d_in[14];
  const float* st_bo  = (const float*)d_in[15];
  const float* ln2_g  = (const float*)d_in[16];
  const float* ln2_b  = (const float*)d_in[17];
  const float* idln2_g= (const float*)d_in[18];
  const float* idln2_b= (const float*)d_in[19];
  const float* sa_Wqk = (const float*)d_in[20];
  const float* sa_bqk = (const float*)d_in[21];
  const float* sa_Wv  = (const float*)d_in[22];
  const float* sa_bv  = (const float*)d_in[23];
  const float* sa_Wu  = (const float*)d_in[24];
  const float* sa_bu  = (const float*)d_in[25];
  const float* sa_Wo  = (const float*)d_in[26];
  const float* sa_bo  = (const float*)d_in[27];
  float* out = (float*)d_out;
  float* ws  = (float*)d_ws;

  float* tgt_ln = ws;                 // 1,036,800  (reused as newt)
  float* Qbuf   = ws + 1036800;       // 1,036,800  (reused as Qs)
  float* Vbuf   = ws + 2073600;       // 4,147,200  (reused as Vs)
  float* Ubuf   = ws + 6220800;       // 2,073,600  (reused as s2)
  float* G1     = ws + 8294400;       // 4,147,200  (attn1 gated out; reused attn2)
  float* G2     = ws + 12441600;      // 4,147,200  (local gated out; reused as Us)
  float* t23    = ws + 16588800;      // 2,073,600  (reused as x)
  float* tgtid  = ws + 18662400;      // 1,036,800
  const int M = NBS;
  dim3 blk(256);
  int gx = (M+63)/64;

  // LN1
  ln256_kernel<<<M, 256, 0, stream>>>(tgt, ln1_g, ln1_b, tgt_ln, 256, 0);

  // qv = _tgt @ W_qv : cols [0,256)->Q raw, [256,768)->silu->V[:, :512]
  gemm64_kernel<0,0><<<dim3(gx, 4), blk, 0, stream>>>(tgt_ln,256, W_qv,    768, b_qv,     Qbuf,256,  0,   M,256);
  gemm64_kernel<1,0><<<dim3(gx, 8), blk, 0, stream>>>(tgt_ln,256, W_qv+256,768, b_qv+256, Vbuf,1024, 0,   M,256);
  // silu(curr_U)
  gemm64_kernel<1,0><<<dim3(gx, 8), blk, 0, stream>>>(tgt_ln,256, W_u,     512, b_u,      Ubuf,512,  0,   M,256);
  // g_ID_V = silu(id_emb @ W_idv) -> V[:, 512:]
  gemm64_kernel<1,0><<<dim3(gx, 8), blk, 0, stream>>>(id_emb,256, W_idv,   512, b_idv,    Vbuf,1024, 512, M,256);

  // global attn 1 (gate width 512) and local attn
  flash_attn_kernel<<<dim3(64,8,2), blk, 0, stream>>>(Qbuf, Qbuf, Vbuf, Ubuf, G1, 512);
  local_attn_kernel<<<dim3(45,8,2), blk, 0, stream>>>(Qbuf, Vbuf, Ubuf, Wrel, brel, G2);

  // t23 = G1 @ lt_Wo + lt_bo + G2 @ st_Wo + st_bo
  gemm64_kernel<0,0><<<dim3(gx, 8), blk, 0, stream>>>(G1,1024, lt_Wo,512, lt_bo, t23,512,0, M,1024);
  gemm64_kernel<0,1><<<dim3(gx, 8), blk, 0, stream>>>(G2,1024, st_Wo,512, st_bo, t23,512,0, M,1024);

  // residuals
  float* newt = tgt_ln;
  resid_split_kernel<<<(M*256+255)/256, blk, 0, stream>>>(tgt, t23, newt, tgtid);

  // x = [ln(newt), ln(tgtid)]
  float* xbuf = t23;
  ln256_kernel<<<M, 256, 0, stream>>>(newt,  ln2_g,   ln2_b,   xbuf, 512, 0);
  ln256_kernel<<<M, 256, 0, stream>>>(tgtid, idln2_g, idln2_b, xbuf, 512, 256);

  // Qs / Vs / Us
  float* Qs = Qbuf; float* Vs = Vbuf; float* Us = G2;
  gemm64_kernel<0,0><<<dim3(gx, 4),  blk, 0, stream>>>(xbuf,512, sa_Wqk,256,  sa_bqk, Qs,256,  0, M,512);
  gemm64_kernel<1,0><<<dim3(gx, 16), blk, 0, stream>>>(xbuf,512, sa_Wv,1024,  sa_bv,  Vs,1024, 0, M,512);
  gemm64_kernel<1,0><<<dim3(gx, 16), blk, 0, stream>>>(xbuf,512, sa_Wu,1024,  sa_bu,  Us,1024, 0, M,512);

  // global attn 2 (gate width 1024)
  flash_attn_kernel<<<dim3(64,8,2), blk, 0, stream>>>(Qs, Qs, Vs, Us, G1, 1024);

  // s2 = gated @ sa_Wo + sa_bo
  float* s2 = Ubuf;
  gemm64_kernel<0,0><<<dim3(gx, 8), blk, 0, stream>>>(G1,1024, sa_Wo,512, sa_bo, s2,512,0, M,1024);

  final_add_kernel<<<(M*256+255)/256, blk, 0, stream>>>(newt, tgtid, s2, out);
}

// Round 3
// 1074.873 us; speedup vs baseline: 3.1442x; 2.0228x over previous
//
#include <hip/hip_runtime.h>
#include <math.h>

#define NTOK 2025
#define NBS  4050   // NTOK * BS
#define BSZ  2

typedef __attribute__((ext_vector_type(8))) short bf16x8;
typedef __attribute__((ext_vector_type(4))) float f32x4;

__device__ __forceinline__ float silu_f(float v){ return v / (1.f + __expf(-v)); }

__device__ __forceinline__ unsigned short bf16_rne(float f){
  union { float f; unsigned u; } v; v.f = f;
  unsigned u = v.u;
  return (unsigned short)((u + 0x7FFFu + ((u >> 16) & 1u)) >> 16);
}

// ---------------- LayerNorm over C=256 ----------------
__global__ __launch_bounds__(256) void ln256_kernel(
    const float* __restrict__ in, const float* __restrict__ g,
    const float* __restrict__ bta, float* __restrict__ out,
    int ldout, int col0)
{
  int row = blockIdx.x;
  int t = threadIdx.x;
  float x = in[(size_t)row*256 + t];
  float s = x, s2 = x*x;
  #pragma unroll
  for (int o=32; o>0; o>>=1){ s += __shfl_xor(s,o); s2 += __shfl_xor(s2,o); }
  __shared__ float w1[4], w2[4];
  __shared__ float mean_s, rstd_s;
  int wid = t>>6, lane = t&63;
  if (lane==0){ w1[wid]=s; w2[wid]=s2; }
  __syncthreads();
  if (t==0){
    float S  = w1[0]+w1[1]+w1[2]+w1[3];
    float S2 = w2[0]+w2[1]+w2[2]+w2[3];
    float m = S*(1.f/256.f);
    float v = S2*(1.f/256.f) - m*m;
    mean_s = m; rstd_s = rsqrtf(v + 1e-5f);
  }
  __syncthreads();
  out[(size_t)row*ldout + col0 + t] = (x-mean_s)*rstd_s*g[t] + bta[t];
}

// ---------------- fp32 GEMM: C = A(MxK) @ B(KxN) + bias, EPI: 0 none 1 silu; ACC adds into C
template<int EPI, int ACC>
__global__ __launch_bounds__(256) void gemm64_kernel(
    const float* __restrict__ A, int lda,
    const float* __restrict__ B, int ldb,
    const float* __restrict__ bias,
    float* __restrict__ C, int ldc, int col0,
    int M, int K)
{
  __shared__ float As[16][64];
  __shared__ float Bs[16][64];
  const int m0 = blockIdx.x*64, n0 = blockIdx.y*64;
  const int t = threadIdx.x;
  const int ty = t>>4, tx = t&15;
  const int ar = t>>2, ak = (t&3)<<2;
  const int bk = t>>4, bc = (t&15)<<2;
  float acc[4][4] = {};
  for (int k0=0; k0<K; k0+=16){
    float4 a = make_float4(0.f,0.f,0.f,0.f);
    if (m0+ar < M) a = *reinterpret_cast<const float4*>(A + (size_t)(m0+ar)*lda + k0 + ak);
    As[ak+0][ar]=a.x; As[ak+1][ar]=a.y; As[ak+2][ar]=a.z; As[ak+3][ar]=a.w;
    float4 bv = *reinterpret_cast<const float4*>(B + (size_t)(k0+bk)*ldb + n0 + bc);
    *reinterpret_cast<float4*>(&Bs[bk][bc]) = bv;
    __syncthreads();
    #pragma unroll
    for (int k=0;k<16;k++){
      float4 a4 = *reinterpret_cast<const float4*>(&As[k][ty<<2]);
      float4 b4 = *reinterpret_cast<const float4*>(&Bs[k][tx<<2]);
      float av[4] = {a4.x,a4.y,a4.z,a4.w};
      float bw[4] = {b4.x,b4.y,b4.z,b4.w};
      #pragma unroll
      for (int i=0;i<4;i++)
        #pragma unroll
        for (int j=0;j<4;j++) acc[i][j] += av[i]*bw[j];
    }
    __syncthreads();
  }
  #pragma unroll
  for (int i=0;i<4;i++){
    int row = m0 + (ty<<2) + i;
    if (row >= M) break;
    #pragma unroll
    for (int j=0;j<4;j++){
      int col = n0 + (tx<<2) + j;
      float v = acc[i][j] + bias[col];
      if (ACC) v += C[(size_t)row*ldc + col0 + col];
      if (EPI==1) v = silu_f(v);
      C[(size_t)row*ldc + col0 + col] = v;
    }
  }
}

// ---------------- MFMA flash attention ----------------
// 64-query tile per block, 4 waves, wave w owns queries [r0+16w, r0+16w+16).
// Q,K layout: (n*2+b)*256 + h*32 + d ; V layout: (n*2+b)*1024 + h*128 + e
// mfma_f32_16x16x32_bf16: A[row=l&15][k=(l>>4)*8+j], B[k=(l>>4)*8+j][col=l&15],
// C/D: col=l&15, row=(l>>4)*4+reg  (verified layout per learn_hip m89)
__global__ __launch_bounds__(256) void flash_mfma_kernel(
    const float* __restrict__ Qp, const float* __restrict__ Vp, const float* __restrict__ Ug,
    float* __restrict__ Out, int gateW)
{
  __shared__ __align__(16) unsigned short Ks[64*40];   // K tile bf16 [key][d], stride 40
  __shared__ __align__(16) unsigned Vt2[128*36];       // V^T pair-packed [dv][kp], stride 36 words
  __shared__ __align__(16) unsigned short Pb[4*16*72]; // per-wave P strip [q][key], stride 72

  const int t  = threadIdx.x;
  const int w  = t >> 6;
  const int l  = t & 63;
  const int lr = l & 15;   // frag col lane
  const int lg = l >> 4;   // frag k/row group
  const int h  = blockIdx.y, b = blockIdx.z;
  const int r0 = blockIdx.x * 64;
  const float scale = 0.17677669529663687f; // 1/sqrt(32)

  // Q A-frag: lane holds Q[q=r0+16w+lr][d=lg*8+j], scaled, bf16
  bf16x8 qf;
  {
    int n = r0 + w*16 + lr;
    float tmp[8];
    if (n < NTOK){
      const float4* q4 = reinterpret_cast<const float4*>(Qp + (size_t)(n*2+b)*256 + h*32 + lg*8);
      float4 a = q4[0], c = q4[1];
      tmp[0]=a.x; tmp[1]=a.y; tmp[2]=a.z; tmp[3]=a.w;
      tmp[4]=c.x; tmp[5]=c.y; tmp[6]=c.z; tmp[7]=c.w;
    } else {
      #pragma unroll
      for (int j=0;j<8;j++) tmp[j]=0.f;
    }
    #pragma unroll
    for (int j=0;j<8;j++) ((unsigned short*)&qf)[j] = bf16_rne(tmp[j]*scale);
  }

  f32x4 acc[8];
  #pragma unroll
  for (int i=0;i<8;i++) acc[i] = (f32x4){0.f,0.f,0.f,0.f};
  float mrun[4], lrun[4];
  #pragma unroll
  for (int r=0;r<4;r++){ mrun[r] = -1e30f; lrun[r] = 0.f; }

  const f32x4 zero4 = (f32x4){0.f,0.f,0.f,0.f};
  const int NT = (NTOK + 63)/64;  // 32

  for (int kt=0; kt<NT; kt++){
    const int k0 = kt*64;
    __syncthreads();

    // ---- stage K tile: Ks[key][d] bf16 ----
    {
      int key = t & 63, dh = t >> 6;   // d-base = dh*8
      int n = k0 + key;
      float tmp[8];
      if (n < NTOK){
        const float4* k4 = reinterpret_cast<const float4*>(Qp + (size_t)(n*2+b)*256 + h*32 + dh*8);
        float4 a = k4[0], c = k4[1];
        tmp[0]=a.x; tmp[1]=a.y; tmp[2]=a.z; tmp[3]=a.w;
        tmp[4]=c.x; tmp[5]=c.y; tmp[6]=c.z; tmp[7]=c.w;
      } else {
        #pragma unroll
        for (int j=0;j<8;j++) tmp[j]=0.f;
      }
      bf16x8 kv;
      #pragma unroll
      for (int j=0;j<8;j++) ((unsigned short*)&kv)[j] = bf16_rne(tmp[j]);
      *reinterpret_cast<bf16x8*>(&Ks[key*40 + dh*8]) = kv;
    }

    // ---- stage V tile transposed pair-packed: Vt2[dv][kp] = {V[2kp][dv], V[2kp+1][dv]} ----
    {
      int kp = t & 31, dh = t >> 5;    // dv-base = dh*16
      int n0 = k0 + kp*2, n1 = n0 + 1;
      const float* v0 = Vp + (size_t)(n0*2+b)*1024 + h*128 + dh*16;
      const float* v1 = Vp + (size_t)(n1*2+b)*1024 + h*128 + dh*16;
      float r0v[16], r1v[16];
      #pragma unroll
      for (int q=0;q<4;q++){
        float4 a = (n0<NTOK)? reinterpret_cast<const float4*>(v0)[q] : make_float4(0,0,0,0);
        float4 c = (n1<NTOK)? reinterpret_cast<const float4*>(v1)[q] : make_float4(0,0,0,0);
        r0v[q*4+0]=a.x; r0v[q*4+1]=a.y; r0v[q*4+2]=a.z; r0v[q*4+3]=a.w;
        r1v[q*4+0]=c.x; r1v[q*4+1]=c.y; r1v[q*4+2]=c.z; r1v[q*4+3]=c.w;
      }
      #pragma unroll
      for (int e=0;e<16;e++){
        unsigned pk = (unsigned)bf16_rne(r0v[e]) | ((unsigned)bf16_rne(r1v[e]) << 16);
        Vt2[(dh*16+e)*36 + kp] = pk;
      }
    }
    __syncthreads();

    // ---- QK^T: 4 MFMAs, frag f covers keys [k0+16f, k0+16f+16) ----
    f32x4 s[4];
    #pragma unroll
    for (int f=0;f<4;f++){
      bf16x8 kb = *reinterpret_cast<const bf16x8*>(&Ks[(16*f + lr)*40 + lg*8]);
      s[f] = __builtin_amdgcn_mfma_f32_16x16x32_bf16(qf, kb, zero4, 0, 0, 0);
    }
    if (k0 + 64 > NTOK){
      #pragma unroll
      for (int f=0;f<4;f++){
        if (k0 + 16*f + lr >= NTOK){ s[f][0]=-1e30f; s[f][1]=-1e30f; s[f][2]=-1e30f; s[f][3]=-1e30f; }
      }
    }

    // ---- online softmax (rows = lg*4+r, cols spread over 16 lanes x 4 frags) ----
    float alpha[4];
    #pragma unroll
    for (int r=0;r<4;r++){
      float tm = fmaxf(fmaxf(s[0][r], s[1][r]), fmaxf(s[2][r], s[3][r]));
      #pragma unroll
      for (int off=1; off<16; off<<=1) tm = fmaxf(tm, __shfl_xor(tm, off));
      float mn = fmaxf(mrun[r], tm);
      alpha[r] = __expf(mrun[r] - mn);
      mrun[r] = mn;
      float ps = 0.f;
      #pragma unroll
      for (int f=0;f<4;f++){
        float p = __expf(s[f][r] - mn);
        s[f][r] = p; ps += p;
      }
      #pragma unroll
      for (int off=1; off<16; off<<=1) ps += __shfl_xor(ps, off);
      lrun[r] = lrun[r]*alpha[r] + ps;
    }

    // ---- P -> per-wave LDS (transpose to A-frag layout) ----
    unsigned short* pb = &Pb[w*16*72];
    #pragma unroll
    for (int f=0;f<4;f++)
      #pragma unroll
      for (int r=0;r<4;r++)
        pb[(lg*4+r)*72 + 16*f + lr] = bf16_rne(s[f][r]);
    bf16x8 pa0 = *reinterpret_cast<const bf16x8*>(&pb[lr*72 + 0*32 + lg*8]);
    bf16x8 pa1 = *reinterpret_cast<const bf16x8*>(&pb[lr*72 + 1*32 + lg*8]);

    // ---- rescale + PV (16 MFMAs) ----
    #pragma unroll
    for (int i=0;i<8;i++){
      #pragma unroll
      for (int r=0;r<4;r++) acc[i][r] *= alpha[r];
    }
    #pragma unroll
    for (int c=0;c<8;c++){
      bf16x8 vb0 = *reinterpret_cast<const bf16x8*>(&Vt2[(c*16+lr)*36 + 0*16 + lg*4]);
      acc[c] = __builtin_amdgcn_mfma_f32_16x16x32_bf16(pa0, vb0, acc[c], 0, 0, 0);
    }
    #pragma unroll
    for (int c=0;c<8;c++){
      bf16x8 vb1 = *reinterpret_cast<const bf16x8*>(&Vt2[(c*16+lr)*36 + 1*16 + lg*4]);
      acc[c] = __builtin_amdgcn_mfma_f32_16x16x32_bf16(pa1, vb1, acc[c], 0, 0, 0);
    }
  }

  // ---- epilogue: 1/l, gate, store. acc row = lg*4+r, col dv = c*16+lr ----
  float linv[4];
  #pragma unroll
  for (int r=0;r<4;r++) linv[r] = 1.f / lrun[r];
  #pragma unroll
  for (int r=0;r<4;r++){
    int n = r0 + w*16 + lg*4 + r;
    if (n >= NTOK) continue;
    size_t rb = (size_t)(n*2+b);
    const float* ugr = Ug + rb*gateW;
    float* orow = Out + rb*1024 + h*128;
    #pragma unroll
    for (int c=0;c<8;c++){
      int dv = c*16 + lr;
      int ch = h*128 + dv;
      float v = acc[c][r]*linv[r];
      if (ch < gateW) v *= ugr[ch];
      orow[dv] = v;
    }
  }
}

// ---------------- local windowed attention (15x15), one block per (b,h,y)
__global__ __launch_bounds__(256) void local_attn_kernel(
    const float* __restrict__ Qp, const float* __restrict__ Vp, const float* __restrict__ Ug,
    const float* __restrict__ Wrel, const float* __restrict__ brel_g, float* __restrict__ Out)
{
  __shared__ float qs[45][32];
  __shared__ float sc[45][225];
  __shared__ float buf[59*128];
  const int t = threadIdx.x;
  const int y = blockIdx.x, h = blockIdx.y, b = blockIdx.z;
  const float scale = 0.17677669529663687f;

  for (int idx=t; idx<45*8; idx+=256){
    int px = idx>>3, d4 = (idx&7)<<2;
    int n = y*45 + px;
    float4 q = *reinterpret_cast<const float4*>(Qp + (size_t)(n*2+b)*256 + h*32 + d4);
    qs[px][d4+0]=q.x*scale; qs[px][d4+1]=q.y*scale; qs[px][d4+2]=q.z*scale; qs[px][d4+3]=q.w*scale;
  }

  float* ks  = buf;
  float* wr  = buf + 59*32;
  float* brs = buf + 59*32 + 15*32;

  for (int dy=0; dy<15; dy++){
    int yy = y + dy - 7;
    __syncthreads();
    if (yy >= 0 && yy < 45){
      for (int idx=t; idx<59*8; idx+=256){
        int xxp = idx>>3, d4 = (idx&7)<<2;
        int xx = xxp - 7;
        float4 kv = make_float4(0,0,0,0);
        if (xx >= 0 && xx < 45)
          kv = *reinterpret_cast<const float4*>(Qp + (size_t)((yy*45+xx)*2+b)*256 + h*32 + d4);
        *reinterpret_cast<float4*>(&ks[xxp*32 + d4]) = kv;
      }
      for (int idx=t; idx<15*8; idx+=256){
        int dx = idx>>3, d4 = (idx&7)<<2;
        *reinterpret_cast<float4*>(&wr[dx*32+d4]) =
          *reinterpret_cast<const float4*>(Wrel + ((size_t)h*225 + dy*15+dx)*32 + d4);
      }
      if (t < 15) brs[t] = brel_g[h*225 + dy*15 + t];
      __syncthreads();
      for (int idx=t; idx<675; idx+=256){
        int px = idx/15, dx = idx - px*15;
        int xx = px + dx - 7;
        float s = -1e9f;
        if (xx >= 0 && xx < 45){
          const float4* q4 = reinterpret_cast<const float4*>(&qs[px][0]);
          const float4* k4 = reinterpret_cast<const float4*>(&ks[(px+dx)*32]);
          const float4* w4 = reinterpret_cast<const float4*>(&wr[dx*32]);
          float acc = 0.f;
          #pragma unroll
          for (int d=0; d<8; d++){
            float4 q = q4[d], kv = k4[d], wv = w4[d];
            acc += q.x*(kv.x+wv.x) + q.y*(kv.y+wv.y) + q.z*(kv.z+wv.z) + q.w*(kv.w+wv.w);
          }
          s = acc + brs[dx];
        }
        sc[px][dy*15+dx] = s;
      }
    } else {
      for (int idx=t; idx<675; idx+=256){
        int px = idx/15, dx = idx - px*15;
        sc[px][dy*15+dx] = -1e9f;
      }
    }
  }
  __syncthreads();

  {
    int grp = t>>5, lane = t&31;
    for (int px = grp; px < 45; px += 8){
      float m = -1e30f;
      for (int o=lane; o<225; o+=32) m = fmaxf(m, sc[px][o]);
      #pragma unroll
      for (int off=16; off>0; off>>=1) m = fmaxf(m, __shfl_xor(m, off));
      float sum = 0.f;
      for (int o=lane; o<225; o+=32){ float p = __expf(sc[px][o]-m); sc[px][o]=p; sum += p; }
      #pragma unroll
      for (int off=16; off>0; off>>=1) sum += __shfl_xor(sum, off);
      float inv = 1.f/sum;
      for (int o=lane; o<225; o+=32) sc[px][o] *= inv;
    }
  }
  __syncthreads();

  float4 acc[6];
  #pragma unroll
  for (int i=0;i<6;i++) acc[i]=make_float4(0.f,0.f,0.f,0.f);
  float* vsm = buf;
  for (int dy=0; dy<15; dy++){
    int yy = y + dy - 7;
    if (yy < 0 || yy >= 45) continue;
    __syncthreads();
    for (int idx=t; idx<59*32; idx+=256){
      int xxp = idx>>5, e4 = (idx&31)<<2;
      int xx = xxp - 7;
      float4 v = make_float4(0.f,0.f,0.f,0.f);
      if (xx>=0 && xx<45)
        v = *reinterpret_cast<const float4*>(Vp + (size_t)((yy*45+xx)*2+b)*1024 + h*128 + e4);
      *reinterpret_cast<float4*>(&vsm[xxp*128 + e4]) = v;
    }
    __syncthreads();
    #pragma unroll
    for (int k=0;k<6;k++){
      int slot = t + 256*k;
      if (slot >= 1440) break;
      int px = slot>>5, e4 = (slot&31)<<2;
      float4 a = acc[k];
      #pragma unroll
      for (int dx=0; dx<15; dx++){
        float p = sc[px][dy*15+dx];
        float4 v = *reinterpret_cast<const float4*>(&vsm[(px+dx)*128 + e4]);
        a.x += p*v.x; a.y += p*v.y; a.z += p*v.z; a.w += p*v.w;
      }
      acc[k] = a;
    }
  }

  #pragma unroll
  for (int k=0;k<6;k++){
    int slot = t + 256*k;
    if (slot >= 1440) break;
    int px = slot>>5, e4 = (slot&31)<<2;
    int n = y*45 + px;
    size_t rb = (size_t)(n*2+b);
    int ch = h*128 + e4;
    float4 a = acc[k];
    if (ch < 512){
      float4 g = *reinterpret_cast<const float4*>(Ug + rb*512 + ch);
      a.x *= g.x; a.y *= g.y; a.z *= g.z; a.w *= g.w;
    }
    *reinterpret_cast<float4*>(Out + rb*1024 + ch) = a;
  }
}

// ---------------- residual split
__global__ __launch_bounds__(256) void resid_split_kernel(
    const float* __restrict__ tgt, const float* __restrict__ t23,
    float* __restrict__ newt, float* __restrict__ tgtid)
{
  int idx = blockIdx.x*256 + threadIdx.x;
  if (idx >= NBS*256) return;
  int row = idx >> 8, c = idx & 255;
  newt[idx]  = tgt[idx] + t23[(size_t)row*512 + c];
  tgtid[idx] = t23[(size_t)row*512 + 256 + c];
}

// ---------------- final add
__global__ __launch_bounds__(256) void final_add_kernel(
    const float* __restrict__ newt, const float* __restrict__ tgtid,
    const float* __restrict__ s2, float* __restrict__ out)
{
  int idx = blockIdx.x*256 + threadIdx.x;
  if (idx >= NBS*256) return;
  int row = idx >> 8, c = idx & 255;
  out[idx]            = newt[idx]  + s2[(size_t)row*512 + c];
  out[NBS*256 + idx]  = tgtid[idx] + s2[(size_t)row*512 + 256 + c];
}

extern "C" void kernel_launch(void* const* d_in, const int* in_sizes, int n_in,
                              void* d_out, int out_size, void* d_ws, size_t ws_size,
                              hipStream_t stream)
{
  const float* tgt    = (const float*)d_in[0];
  const float* id_emb = (const float*)d_in[1];
  const float* ln1_g  = (const float*)d_in[2];
  const float* ln1_b  = (const float*)d_in[3];
  const float* W_qv   = (const float*)d_in[4];
  const float* b_qv   = (const float*)d_in[5];
  const float* W_u    = (const float*)d_in[6];
  const float* b_u    = (const float*)d_in[7];
  const float* W_idv  = (const float*)d_in[8];
  const float* b_idv  = (const float*)d_in[9];
  const float* lt_Wo  = (const float*)d_in[10];
  const float* lt_bo  = (const float*)d_in[11];
  const float* Wrel   = (const float*)d_in[12];
  const float* brel   = (const float*)d_in[13];
  const float* st_Wo  = (const float*)d_in[14];
  const float* st_bo  = (const float*)d_in[15];
  const float* ln2_g  = (const float*)d_in[16];
  const float* ln2_b  = (const float*)d_in[17];
  const float* idln2_g= (const float*)d_in[18];
  const float* idln2_b= (const float*)d_in[19];
  const float* sa_Wqk = (const float*)d_in[20];
  const float* sa_bqk = (const float*)d_in[21];
  const float* sa_Wv  = (const float*)d_in[22];
  const float* sa_bv  = (const float*)d_in[23];
  const float* sa_Wu  = (const float*)d_in[24];
  const float* sa_bu  = (const float*)d_in[25];
  const float* sa_Wo  = (const float*)d_in[26];
  const float* sa_bo  = (const float*)d_in[27];
  float* out = (float*)d_out;
  float* ws  = (float*)d_ws;

  float* tgt_ln = ws;                 // reused as newt
  float* Qbuf   = ws + 1036800;       // reused as Qs
  float* Vbuf   = ws + 2073600;       // reused as Vs
  float* Ubuf   = ws + 6220800;       // reused as s2
  float* G1     = ws + 8294400;
  float* G2     = ws + 12441600;      // reused as Us
  float* t23    = ws + 16588800;      // reused as x
  float* tgtid  = ws + 18662400;
  const int M = NBS;
  dim3 blk(256);
  int gx = (M+63)/64;

  ln256_kernel<<<M, 256, 0, stream>>>(tgt, ln1_g, ln1_b, tgt_ln, 256, 0);

  gemm64_kernel<0,0><<<dim3(gx, 4), blk, 0, stream>>>(tgt_ln,256, W_qv,    768, b_qv,     Qbuf,256,  0,   M,256);
  gemm64_kernel<1,0><<<dim3(gx, 8), blk, 0, stream>>>(tgt_ln,256, W_qv+256,768, b_qv+256, Vbuf,1024, 0,   M,256);
  gemm64_kernel<1,0><<<dim3(gx, 8), blk, 0, stream>>>(tgt_ln,256, W_u,     512, b_u,      Ubuf,512,  0,   M,256);
  gemm64_kernel<1,0><<<dim3(gx, 8), blk, 0, stream>>>(id_emb,256, W_idv,   512, b_idv,    Vbuf,1024, 512, M,256);

  flash_mfma_kernel<<<dim3(32,8,2), blk, 0, stream>>>(Qbuf, Vbuf, Ubuf, G1, 512);
  local_attn_kernel<<<dim3(45,8,2), blk, 0, stream>>>(Qbuf, Vbuf, Ubuf, Wrel, brel, G2);

  gemm64_kernel<0,0><<<dim3(gx, 8), blk, 0, stream>>>(G1,1024, lt_Wo,512, lt_bo, t23,512,0, M,1024);
  gemm64_kernel<0,1><<<dim3(gx, 8), blk, 0, stream>>>(G2,1024, st_Wo,512, st_bo, t23,512,0, M,1024);

  float* newt = tgt_ln;
  resid_split_kernel<<<(M*256+255)/256, blk, 0, stream>>>(tgt, t23, newt, tgtid);

  float* xbuf = t23;
  ln256_kernel<<<M, 256, 0, stream>>>(newt,  ln2_g,   ln2_b,   xbuf, 512, 0);
  ln256_kernel<<<M, 256, 0, stream>>>(tgtid, idln2_g, idln2_b, xbuf, 512, 256);

  float* Qs = Qbuf; float* Vs = Vbuf; float* Us = G2;
  gemm64_kernel<0,0><<<dim3(gx, 4),  blk, 0, stream>>>(xbuf,512, sa_Wqk,256,  sa_bqk, Qs,256,  0, M,512);
  gemm64_kernel<1,0><<<dim3(gx, 16), blk, 0, stream>>>(xbuf,512, sa_Wv,1024,  sa_bv,  Vs,1024, 0, M,512);
  gemm64_kernel<1,0><<<dim3(gx, 16), blk, 0, stream>>>(xbuf,512, sa_Wu,1024,  sa_bu,  Us,1024, 0, M,512);

  flash_mfma_kernel<<<dim3(32,8,2), blk, 0, stream>>>(Qs, Vs, Us, G1, 1024);

  float* s2 = Ubuf;
  gemm64_kernel<0,0><<<dim3(gx, 8), blk, 0, stream>>>(G1,1024, sa_Wo,512, sa_bo, s2,512,0, M,1024);

  final_add_kernel<<<(M*256+255)/256, blk, 0, stream>>>(newt, tgtid, s2, out);
}

// Round 4
// 990.261 us; speedup vs baseline: 3.4129x; 1.0854x over previous
//
#include <hip/hip_runtime.h>
#include <math.h>

#define NTOK 2025
#define NBS  4050   // NTOK * BS
#define BSZ  2

typedef __attribute__((ext_vector_type(8))) short bf16x8;
typedef __attribute__((ext_vector_type(4))) float f32x4;

__device__ __forceinline__ float silu_f(float v){ return v / (1.f + __expf(-v)); }

__device__ __forceinline__ unsigned short bf16_rne(float f){
  union { float f; unsigned u; } v; v.f = f;
  unsigned u = v.u;
  return (unsigned short)((u + 0x7FFFu + ((u >> 16) & 1u)) >> 16);
}

__device__ __forceinline__ bf16x8 pack_bf8(const float* v){
  bf16x8 r;
  #pragma unroll
  for (int j=0;j<8;j++) ((unsigned short*)&r)[j] = bf16_rne(v[j]);
  return r;
}

// ---------------- LayerNorm over C=256 ----------------
__global__ __launch_bounds__(256) void ln256_kernel(
    const float* __restrict__ in, const float* __restrict__ g,
    const float* __restrict__ bta, float* __restrict__ out,
    int ldout, int col0)
{
  int row = blockIdx.x;
  int t = threadIdx.x;
  float x = in[(size_t)row*256 + t];
  float s = x, s2 = x*x;
  #pragma unroll
  for (int o=32; o>0; o>>=1){ s += __shfl_xor(s,o); s2 += __shfl_xor(s2,o); }
  __shared__ float w1[4], w2[4];
  __shared__ float mean_s, rstd_s;
  int wid = t>>6, lane = t&63;
  if (lane==0){ w1[wid]=s; w2[wid]=s2; }
  __syncthreads();
  if (t==0){
    float S  = w1[0]+w1[1]+w1[2]+w1[3];
    float S2 = w2[0]+w2[1]+w2[2]+w2[3];
    float m = S*(1.f/256.f);
    float v = S2*(1.f/256.f) - m*m;
    mean_s = m; rstd_s = rsqrtf(v + 1e-5f);
  }
  __syncthreads();
  out[(size_t)row*ldout + col0 + t] = (x-mean_s)*rstd_s*g[t] + bta[t];
}

// ---------------- fp32 GEMM: C = A(MxK) @ B(KxN) + bias, EPI: 0 none 1 silu; ACC adds into C
template<int EPI, int ACC>
__global__ __launch_bounds__(256) void gemm64_kernel(
    const float* __restrict__ A, int lda,
    const float* __restrict__ B, int ldb,
    const float* __restrict__ bias,
    float* __restrict__ C, int ldc, int col0,
    int M, int K)
{
  __shared__ float As[16][64];
  __shared__ float Bs[16][64];
  const int m0 = blockIdx.x*64, n0 = blockIdx.y*64;
  const int t = threadIdx.x;
  const int ty = t>>4, tx = t&15;
  const int ar = t>>2, ak = (t&3)<<2;
  const int bk = t>>4, bc = (t&15)<<2;
  float acc[4][4] = {};
  for (int k0=0; k0<K; k0+=16){
    float4 a = make_float4(0.f,0.f,0.f,0.f);
    if (m0+ar < M) a = *reinterpret_cast<const float4*>(A + (size_t)(m0+ar)*lda + k0 + ak);
    As[ak+0][ar]=a.x; As[ak+1][ar]=a.y; As[ak+2][ar]=a.z; As[ak+3][ar]=a.w;
    float4 bv = *reinterpret_cast<const float4*>(B + (size_t)(k0+bk)*ldb + n0 + bc);
    *reinterpret_cast<float4*>(&Bs[bk][bc]) = bv;
    __syncthreads();
    #pragma unroll
    for (int k=0;k<16;k++){
      float4 a4 = *reinterpret_cast<const float4*>(&As[k][ty<<2]);
      float4 b4 = *reinterpret_cast<const float4*>(&Bs[k][tx<<2]);
      float av[4] = {a4.x,a4.y,a4.z,a4.w};
      float bw[4] = {b4.x,b4.y,b4.z,b4.w};
      #pragma unroll
      for (int i=0;i<4;i++)
        #pragma unroll
        for (int j=0;j<4;j++) acc[i][j] += av[i]*bw[j];
    }
    __syncthreads();
  }
  #pragma unroll
  for (int i=0;i<4;i++){
    int row = m0 + (ty<<2) + i;
    if (row >= M) break;
    #pragma unroll
    for (int j=0;j<4;j++){
      int col = n0 + (tx<<2) + j;
      float v = acc[i][j] + bias[col];
      if (ACC) v += C[(size_t)row*ldc + col0 + col];
      if (EPI==1) v = silu_f(v);
      C[(size_t)row*ldc + col0 + col] = v;
    }
  }
}

// ---------------- MFMA flash attention (unchanged, verified) ----------------
__global__ __launch_bounds__(256) void flash_mfma_kernel(
    const float* __restrict__ Qp, const float* __restrict__ Vp, const float* __restrict__ Ug,
    float* __restrict__ Out, int gateW)
{
  __shared__ __align__(16) unsigned short Ks[64*40];   // K tile bf16 [key][d], stride 40
  __shared__ __align__(16) unsigned Vt2[128*36];       // V^T pair-packed [dv][kp], stride 36 words
  __shared__ __align__(16) unsigned short Pb[4*16*72]; // per-wave P strip [q][key], stride 72

  const int t  = threadIdx.x;
  const int w  = t >> 6;
  const int l  = t & 63;
  const int lr = l & 15;
  const int lg = l >> 4;
  const int h  = blockIdx.y, b = blockIdx.z;
  const int r0 = blockIdx.x * 64;
  const float scale = 0.17677669529663687f;

  bf16x8 qf;
  {
    int n = r0 + w*16 + lr;
    float tmp[8];
    if (n < NTOK){
      const float4* q4 = reinterpret_cast<const float4*>(Qp + (size_t)(n*2+b)*256 + h*32 + lg*8);
      float4 a = q4[0], c = q4[1];
      tmp[0]=a.x; tmp[1]=a.y; tmp[2]=a.z; tmp[3]=a.w;
      tmp[4]=c.x; tmp[5]=c.y; tmp[6]=c.z; tmp[7]=c.w;
    } else {
      #pragma unroll
      for (int j=0;j<8;j++) tmp[j]=0.f;
    }
    #pragma unroll
    for (int j=0;j<8;j++) ((unsigned short*)&qf)[j] = bf16_rne(tmp[j]*scale);
  }

  f32x4 acc[8];
  #pragma unroll
  for (int i=0;i<8;i++) acc[i] = (f32x4){0.f,0.f,0.f,0.f};
  float mrun[4], lrun[4];
  #pragma unroll
  for (int r=0;r<4;r++){ mrun[r] = -1e30f; lrun[r] = 0.f; }

  const f32x4 zero4 = (f32x4){0.f,0.f,0.f,0.f};
  const int NT = (NTOK + 63)/64;

  for (int kt=0; kt<NT; kt++){
    const int k0 = kt*64;
    __syncthreads();

    {
      int key = t & 63, dh = t >> 6;
      int n = k0 + key;
      float tmp[8];
      if (n < NTOK){
        const float4* k4 = reinterpret_cast<const float4*>(Qp + (size_t)(n*2+b)*256 + h*32 + dh*8);
        float4 a = k4[0], c = k4[1];
        tmp[0]=a.x; tmp[1]=a.y; tmp[2]=a.z; tmp[3]=a.w;
        tmp[4]=c.x; tmp[5]=c.y; tmp[6]=c.z; tmp[7]=c.w;
      } else {
        #pragma unroll
        for (int j=0;j<8;j++) tmp[j]=0.f;
      }
      *reinterpret_cast<bf16x8*>(&Ks[key*40 + dh*8]) = pack_bf8(tmp);
    }

    {
      int kp = t & 31, dh = t >> 5;
      int n0 = k0 + kp*2, n1 = n0 + 1;
      const float* v0 = Vp + (size_t)(n0*2+b)*1024 + h*128 + dh*16;
      const float* v1 = Vp + (size_t)(n1*2+b)*1024 + h*128 + dh*16;
      float r0v[16], r1v[16];
      #pragma unroll
      for (int q=0;q<4;q++){
        float4 a = (n0<NTOK)? reinterpret_cast<const float4*>(v0)[q] : make_float4(0,0,0,0);
        float4 c = (n1<NTOK)? reinterpret_cast<const float4*>(v1)[q] : make_float4(0,0,0,0);
        r0v[q*4+0]=a.x; r0v[q*4+1]=a.y; r0v[q*4+2]=a.z; r0v[q*4+3]=a.w;
        r1v[q*4+0]=c.x; r1v[q*4+1]=c.y; r1v[q*4+2]=c.z; r1v[q*4+3]=c.w;
      }
      #pragma unroll
      for (int e=0;e<16;e++){
        unsigned pk = (unsigned)bf16_rne(r0v[e]) | ((unsigned)bf16_rne(r1v[e]) << 16);
        Vt2[(dh*16+e)*36 + kp] = pk;
      }
    }
    __syncthreads();

    f32x4 s[4];
    #pragma unroll
    for (int f=0;f<4;f++){
      bf16x8 kb = *reinterpret_cast<const bf16x8*>(&Ks[(16*f + lr)*40 + lg*8]);
      s[f] = __builtin_amdgcn_mfma_f32_16x16x32_bf16(qf, kb, zero4, 0, 0, 0);
    }
    if (k0 + 64 > NTOK){
      #pragma unroll
      for (int f=0;f<4;f++){
        if (k0 + 16*f + lr >= NTOK){ s[f][0]=-1e30f; s[f][1]=-1e30f; s[f][2]=-1e30f; s[f][3]=-1e30f; }
      }
    }

    float alpha[4];
    #pragma unroll
    for (int r=0;r<4;r++){
      float tm = fmaxf(fmaxf(s[0][r], s[1][r]), fmaxf(s[2][r], s[3][r]));
      #pragma unroll
      for (int off=1; off<16; off<<=1) tm = fmaxf(tm, __shfl_xor(tm, off));
      float mn = fmaxf(mrun[r], tm);
      alpha[r] = __expf(mrun[r] - mn);
      mrun[r] = mn;
      float ps = 0.f;
      #pragma unroll
      for (int f=0;f<4;f++){
        float p = __expf(s[f][r] - mn);
        s[f][r] = p; ps += p;
      }
      #pragma unroll
      for (int off=1; off<16; off<<=1) ps += __shfl_xor(ps, off);
      lrun[r] = lrun[r]*alpha[r] + ps;
    }

    unsigned short* pb = &Pb[w*16*72];
    #pragma unroll
    for (int f=0;f<4;f++)
      #pragma unroll
      for (int r=0;r<4;r++)
        pb[(lg*4+r)*72 + 16*f + lr] = bf16_rne(s[f][r]);
    bf16x8 pa0 = *reinterpret_cast<const bf16x8*>(&pb[lr*72 + 0*32 + lg*8]);
    bf16x8 pa1 = *reinterpret_cast<const bf16x8*>(&pb[lr*72 + 1*32 + lg*8]);

    #pragma unroll
    for (int i=0;i<8;i++){
      #pragma unroll
      for (int r=0;r<4;r++) acc[i][r] *= alpha[r];
    }
    #pragma unroll
    for (int c=0;c<8;c++){
      bf16x8 vb0 = *reinterpret_cast<const bf16x8*>(&Vt2[(c*16+lr)*36 + 0*16 + lg*4]);
      acc[c] = __builtin_amdgcn_mfma_f32_16x16x32_bf16(pa0, vb0, acc[c], 0, 0, 0);
    }
    #pragma unroll
    for (int c=0;c<8;c++){
      bf16x8 vb1 = *reinterpret_cast<const bf16x8*>(&Vt2[(c*16+lr)*36 + 1*16 + lg*4]);
      acc[c] = __builtin_amdgcn_mfma_f32_16x16x32_bf16(pa1, vb1, acc[c], 0, 0, 0);
    }
  }

  float linv[4];
  #pragma unroll
  for (int r=0;r<4;r++) linv[r] = 1.f / lrun[r];
  #pragma unroll
  for (int r=0;r<4;r++){
    int n = r0 + w*16 + lg*4 + r;
    if (n >= NTOK) continue;
    size_t rb = (size_t)(n*2+b);
    const float* ugr = Ug + rb*gateW;
    float* orow = Out + rb*1024 + h*128;
    #pragma unroll
    for (int c=0;c<8;c++){
      int dv = c*16 + lr;
      int ch = h*128 + dv;
      float v = acc[c][r]*linv[r];
      if (ch < gateW) v *= ugr[ch];
      orow[dv] = v;
    }
  }
}

// ---------------- local windowed attention (15x15), one block per (b,h,y)
// Phase A (scores+rel) now via MFMA: R = Q@Wrel^T once; per dy, banded S = Q@K_dy^T.
// sc[px][o] layout unchanged; phases B (softmax) and C (aggregation) unchanged.
__global__ __launch_bounds__(256) void local_attn_kernel(
    const float* __restrict__ Qp, const float* __restrict__ Vp, const float* __restrict__ Ug,
    const float* __restrict__ Wrel, const float* __restrict__ brel_g, float* __restrict__ Out)
{
  __shared__ float sc[45][225];                 // 40.5 KB
  __shared__ __align__(16) float ubuf[7552];    // 30.2 KB union
  unsigned short* Qs = (unsigned short*)ubuf;   // [48][40] bf16 (scaled Q)
  unsigned short* Ks = Qs + 48*40;              // [48][40] bf16 (K row band)
  unsigned short* Ws = Ks + 48*40;              // [240][40] bf16 (Wrel_h^T-staged)
  float* vsm = ubuf;                            // phase C: [59][128] f32

  const int t = threadIdx.x;
  const int w = t>>6, l = t&63;
  const int lr = l&15, lg = l>>4;
  const int y = blockIdx.x, h = blockIdx.y, b = blockIdx.z;
  const float scale = 0.17677669529663687f;
  const f32x4 zero4 = (f32x4){0.f,0.f,0.f,0.f};

  // init sc to -1e9 (reference mask value)
  for (int i=t; i<45*225; i+=256) (&sc[0][0])[i] = -1e9f;

  // stage Q rows 0..47 (scaled, bf16)
  for (int idx=t; idx<192; idx+=256){
    int row = idx>>2, c = (idx&3)<<3;
    float v[8];
    if (row < 45){
      const float4* p = reinterpret_cast<const float4*>(Qp + (size_t)((y*45+row)*2+b)*256 + h*32 + c);
      float4 a = p[0], d2 = p[1];
      v[0]=a.x*scale; v[1]=a.y*scale; v[2]=a.z*scale; v[3]=a.w*scale;
      v[4]=d2.x*scale; v[5]=d2.y*scale; v[6]=d2.z*scale; v[7]=d2.w*scale;
    } else {
      #pragma unroll
      for (int j=0;j<8;j++) v[j]=0.f;
    }
    *reinterpret_cast<bf16x8*>(&Qs[row*40 + c]) = pack_bf8(v);
  }
  // stage Wrel rows 0..239 (bf16)
  for (int idx=t; idx<960; idx+=256){
    int row = idx>>2, c = (idx&3)<<3;
    float v[8];
    if (row < 225){
      const float4* p = reinterpret_cast<const float4*>(Wrel + ((size_t)h*225 + row)*32 + c);
      float4 a = p[0], d2 = p[1];
      v[0]=a.x; v[1]=a.y; v[2]=a.z; v[3]=a.w;
      v[4]=d2.x; v[5]=d2.y; v[6]=d2.z; v[7]=d2.w;
    } else {
      #pragma unroll
      for (int j=0;j<8;j++) v[j]=0.f;
    }
    *reinterpret_cast<bf16x8*>(&Ws[row*40 + c]) = pack_bf8(v);
  }
  __syncthreads();

  // ---- R pass: R[px][o] = q[px]·wrel[o]; write R+brel at valid slots ----
  for (int fo=w; fo<15; fo+=4){
    bf16x8 wb = *reinterpret_cast<const bf16x8*>(&Ws[(16*fo+lr)*40 + lg*8]);
    int o = 16*fo + lr;
    int dyo = o/15, dxo = o - dyo*15;
    int yy = y + dyo - 7;
    bool ovalid = (o < 225) && (yy >= 0) && (yy < 45);
    float bb = ovalid ? brel_g[h*225+o] : 0.f;
    #pragma unroll
    for (int fa=0; fa<3; fa++){
      bf16x8 qa = *reinterpret_cast<const bf16x8*>(&Qs[(16*fa+lr)*40 + lg*8]);
      f32x4 rr = __builtin_amdgcn_mfma_f32_16x16x32_bf16(qa, wb, zero4, 0, 0, 0);
      if (ovalid){
        #pragma unroll
        for (int r=0;r<4;r++){
          int px = 16*fa + lg*4 + r;
          int xx = px + dxo - 7;
          if (px < 45 && xx >= 0 && xx < 45)
            sc[px][o] = rr[r] + bb;
        }
      }
    }
  }
  __syncthreads();

  // ---- S pass: per dy, banded Q@K_dy^T, accumulate into sc ----
  for (int dy=0; dy<15; dy++){
    int yy = y + dy - 7;
    if (yy < 0 || yy >= 45) continue;    // block-uniform
    __syncthreads();                     // protect Ks from previous readers
    for (int idx=t; idx<192; idx+=256){
      int row = idx>>2, c = (idx&3)<<3;
      float v[8];
      if (row < 45){
        const float4* p = reinterpret_cast<const float4*>(Qp + (size_t)((yy*45+row)*2+b)*256 + h*32 + c);
        float4 a = p[0], d2 = p[1];
        v[0]=a.x; v[1]=a.y; v[2]=a.z; v[3]=a.w;
        v[4]=d2.x; v[5]=d2.y; v[6]=d2.z; v[7]=d2.w;
      } else {
        #pragma unroll
        for (int j=0;j<8;j++) v[j]=0.f;
      }
      *reinterpret_cast<bf16x8*>(&Ks[row*40 + c]) = pack_bf8(v);
    }
    __syncthreads();
    // 7 frag pairs cover the |xx-px|<=7 band
    for (int pi=w; pi<7; pi+=4){
      int fa = (0x2110210u >> (4*pi)) & 7;
      int fb = (0x1201210u >> (4*pi)) & 7;
      bf16x8 qa = *reinterpret_cast<const bf16x8*>(&Qs[(16*fa+lr)*40 + lg*8]);
      bf16x8 kb = *reinterpret_cast<const bf16x8*>(&Ks[(16*fb+lr)*40 + lg*8]);
      f32x4 s = __builtin_amdgcn_mfma_f32_16x16x32_bf16(qa, kb, zero4, 0, 0, 0);
      int xx = 16*fb + lr;
      #pragma unroll
      for (int r=0;r<4;r++){
        int px = 16*fa + lg*4 + r;
        int dx = xx - px + 7;
        if (px < 45 && xx < 45 && dx >= 0 && dx < 15)
          sc[px][dy*15+dx] += s[r];
      }
    }
  }
  __syncthreads();

  // ---- phase B: wave-parallel softmax (unchanged) ----
  {
    int grp = t>>5, lane = t&31;
    for (int px = grp; px < 45; px += 8){
      float m = -1e30f;
      for (int o=lane; o<225; o+=32) m = fmaxf(m, sc[px][o]);
      #pragma unroll
      for (int off=16; off>0; off>>=1) m = fmaxf(m, __shfl_xor(m, off));
      float sum = 0.f;
      for (int o=lane; o<225; o+=32){ float p = __expf(sc[px][o]-m); sc[px][o]=p; sum += p; }
      #pragma unroll
      for (int off=16; off>0; off>>=1) sum += __shfl_xor(sum, off);
      float inv = 1.f/sum;
      for (int o=lane; o<225; o+=32) sc[px][o] *= inv;
    }
  }
  __syncthreads();

  // ---- phase C: aggregation, V row staged in LDS (unchanged) ----
  float4 acc[6];
  #pragma unroll
  for (int i=0;i<6;i++) acc[i]=make_float4(0.f,0.f,0.f,0.f);
  for (int dy=0; dy<15; dy++){
    int yy = y + dy - 7;
    if (yy < 0 || yy >= 45) continue;
    __syncthreads();
    for (int idx=t; idx<59*32; idx+=256){
      int xxp = idx>>5, e4 = (idx&31)<<2;
      int xx = xxp - 7;
      float4 v = make_float4(0.f,0.f,0.f,0.f);
      if (xx>=0 && xx<45)
        v = *reinterpret_cast<const float4*>(Vp + (size_t)((yy*45+xx)*2+b)*1024 + h*128 + e4);
      *reinterpret_cast<float4*>(&vsm[xxp*128 + e4]) = v;
    }
    __syncthreads();
    #pragma unroll
    for (int k=0;k<6;k++){
      int slot = t + 256*k;
      if (slot >= 1440) break;
      int px = slot>>5, e4 = (slot&31)<<2;
      float4 a = acc[k];
      #pragma unroll
      for (int dx=0; dx<15; dx++){
        float p = sc[px][dy*15+dx];
        float4 v = *reinterpret_cast<const float4*>(&vsm[(px+dx)*128 + e4]);
        a.x += p*v.x; a.y += p*v.y; a.z += p*v.z; a.w += p*v.w;
      }
      acc[k] = a;
    }
  }

  #pragma unroll
  for (int k=0;k<6;k++){
    int slot = t + 256*k;
    if (slot >= 1440) break;
    int px = slot>>5, e4 = (slot&31)<<2;
    int n = y*45 + px;
    size_t rb = (size_t)(n*2+b);
    int ch = h*128 + e4;
    float4 a = acc[k];
    if (ch < 512){
      float4 g = *reinterpret_cast<const float4*>(Ug + rb*512 + ch);
      a.x *= g.x; a.y *= g.y; a.z *= g.z; a.w *= g.w;
    }
    *reinterpret_cast<float4*>(Out + rb*1024 + ch) = a;
  }
}

// ---------------- residual split
__global__ __launch_bounds__(256) void resid_split_kernel(
    const float* __restrict__ tgt, const float* __restrict__ t23,
    float* __restrict__ newt, float* __restrict__ tgtid)
{
  int idx = blockIdx.x*256 + threadIdx.x;
  if (idx >= NBS*256) return;
  int row = idx >> 8, c = idx & 255;
  newt[idx]  = tgt[idx] + t23[(size_t)row*512 + c];
  tgtid[idx] = t23[(size_t)row*512 + 256 + c];
}

// ---------------- final add
__global__ __launch_bounds__(256) void final_add_kernel(
    const float* __restrict__ newt, const float* __restrict__ tgtid,
    const float* __restrict__ s2, float* __restrict__ out)
{
  int idx = blockIdx.x*256 + threadIdx.x;
  if (idx >= NBS*256) return;
  int row = idx >> 8, c = idx & 255;
  out[idx]            = newt[idx]  + s2[(size_t)row*512 + c];
  out[NBS*256 + idx]  = tgtid[idx] + s2[(size_t)row*512 + 256 + c];
}

extern "C" void kernel_launch(void* const* d_in, const int* in_sizes, int n_in,
                              void* d_out, int out_size, void* d_ws, size_t ws_size,
                              hipStream_t stream)
{
  const float* tgt    = (const float*)d_in[0];
  const float* id_emb = (const float*)d_in[1];
  const float* ln1_g  = (const float*)d_in[2];
  const float* ln1_b  = (const float*)d_in[3];
  const float* W_qv   = (const float*)d_in[4];
  const float* b_qv   = (const float*)d_in[5];
  const float* W_u    = (const float*)d_in[6];
  const float* b_u    = (const float*)d_in[7];
  const float* W_idv  = (const float*)d_in[8];
  const float* b_idv  = (const float*)d_in[9];
  const float* lt_Wo  = (const float*)d_in[10];
  const float* lt_bo  = (const float*)d_in[11];
  const float* Wrel   = (const float*)d_in[12];
  const float* brel   = (const float*)d_in[13];
  const float* st_Wo  = (const float*)d_in[14];
  const float* st_bo  = (const float*)d_in[15];
  const float* ln2_g  = (const float*)d_in[16];
  const float* ln2_b  = (const float*)d_in[17];
  const float* idln2_g= (const float*)d_in[18];
  const float* idln2_b= (const float*)d_in[19];
  const float* sa_Wqk = (const float*)d_in[20];
  const float* sa_bqk = (const float*)d_in[21];
  const float* sa_Wv  = (const float*)d_in[22];
  const float* sa_bv  = (const float*)d_in[23];
  const float* sa_Wu  = (const float*)d_in[24];
  const float* sa_bu  = (const float*)d_in[25];
  const float* sa_Wo  = (const float*)d_in[26];
  const float* sa_bo  = (const float*)d_in[27];
  float* out = (float*)d_out;
  float* ws  = (float*)d_ws;

  float* tgt_ln = ws;                 // reused as newt
  float* Qbuf   = ws + 1036800;       // reused as Qs
  float* Vbuf   = ws + 2073600;       // reused as Vs
  float* Ubuf   = ws + 6220800;       // reused as s2
  float* G1     = ws + 8294400;
  float* G2     = ws + 12441600;      // reused as Us
  float* t23    = ws + 16588800;      // reused as x
  float* tgtid  = ws + 18662400;
  const int M = NBS;
  dim3 blk(256);
  int gx = (M+63)/64;

  ln256_kernel<<<M, 256, 0, stream>>>(tgt, ln1_g, ln1_b, tgt_ln, 256, 0);

  gemm64_kernel<0,0><<<dim3(gx, 4), blk, 0, stream>>>(tgt_ln,256, W_qv,    768, b_qv,     Qbuf,256,  0,   M,256);
  gemm64_kernel<1,0><<<dim3(gx, 8), blk, 0, stream>>>(tgt_ln,256, W_qv+256,768, b_qv+256, Vbuf,1024, 0,   M,256);
  gemm64_kernel<1,0><<<dim3(gx, 8), blk, 0, stream>>>(tgt_ln,256, W_u,     512, b_u,      Ubuf,512,  0,   M,256);
  gemm64_kernel<1,0><<<dim3(gx, 8), blk, 0, stream>>>(id_emb,256, W_idv,   512, b_idv,    Vbuf,1024, 512, M,256);

  flash_mfma_kernel<<<dim3(32,8,2), blk, 0, stream>>>(Qbuf, Vbuf, Ubuf, G1, 512);
  local_attn_kernel<<<dim3(45,8,2), blk, 0, stream>>>(Qbuf, Vbuf, Ubuf, Wrel, brel, G2);

  gemm64_kernel<0,0><<<dim3(gx, 8), blk, 0, stream>>>(G1,1024, lt_Wo,512, lt_bo, t23,512,0, M,1024);
  gemm64_kernel<0,1><<<dim3(gx, 8), blk, 0, stream>>>(G2,1024, st_Wo,512, st_bo, t23,512,0, M,1024);

  float* newt = tgt_ln;
  resid_split_kernel<<<(M*256+255)/256, blk, 0, stream>>>(tgt, t23, newt, tgtid);

  float* xbuf = t23;
  ln256_kernel<<<M, 256, 0, stream>>>(newt,  ln2_g,   ln2_b,   xbuf, 512, 0);
  ln256_kernel<<<M, 256, 0, stream>>>(tgtid, idln2_g, idln2_b, xbuf, 512, 256);

  float* Qs = Qbuf; float* Vs = Vbuf; float* Us = G2;
  gemm64_kernel<0,0><<<dim3(gx, 4),  blk, 0, stream>>>(xbuf,512, sa_Wqk,256,  sa_bqk, Qs,256,  0, M,512);
  gemm64_kernel<1,0><<<dim3(gx, 16), blk, 0, stream>>>(xbuf,512, sa_Wv,1024,  sa_bv,  Vs,1024, 0, M,512);
  gemm64_kernel<1,0><<<dim3(gx, 16), blk, 0, stream>>>(xbuf,512, sa_Wu,1024,  sa_bu,  Us,1024, 0, M,512);

  flash_mfma_kernel<<<dim3(32,8,2), blk, 0, stream>>>(Qs, Vs, Us, G1, 1024);

  float* s2 = Ubuf;
  gemm64_kernel<0,0><<<dim3(gx, 8), blk, 0, stream>>>(G1,1024, sa_Wo,512, sa_bo, s2,512,0, M,1024);

  final_add_kernel<<<(M*256+255)/256, blk, 0, stream>>>(newt, tgtid, s2, out);
}

// Round 5
// 724.942 us; speedup vs baseline: 4.6620x; 1.3660x over previous
//
#include <hip/hip_runtime.h>
#include <math.h>

#define NTOK 2025
#define NBS  4050   // NTOK * BS
#define BSZ  2

typedef __attribute__((ext_vector_type(8))) short bf16x8;
typedef __attribute__((ext_vector_type(4))) float f32x4;

__device__ __forceinline__ float silu_f(float v){ return v / (1.f + __expf(-v)); }

__device__ __forceinline__ unsigned short bf16_rne(float f){
  union { float f; unsigned u; } v; v.f = f;
  unsigned u = v.u;
  return (unsigned short)((u + 0x7FFFu + ((u >> 16) & 1u)) >> 16);
}

__device__ __forceinline__ bf16x8 pack_bf8(const float* v){
  bf16x8 r;
  #pragma unroll
  for (int j=0;j<8;j++) ((unsigned short*)&r)[j] = bf16_rne(v[j]);
  return r;
}

// ---------------- LayerNorm over C=256 ----------------
__global__ __launch_bounds__(256) void ln256_kernel(
    const float* __restrict__ in, const float* __restrict__ g,
    const float* __restrict__ bta, float* __restrict__ out,
    int ldout, int col0)
{
  int row = blockIdx.x;
  int t = threadIdx.x;
  float x = in[(size_t)row*256 + t];
  float s = x, s2 = x*x;
  #pragma unroll
  for (int o=32; o>0; o>>=1){ s += __shfl_xor(s,o); s2 += __shfl_xor(s2,o); }
  __shared__ float w1[4], w2[4];
  __shared__ float mean_s, rstd_s;
  int wid = t>>6, lane = t&63;
  if (lane==0){ w1[wid]=s; w2[wid]=s2; }
  __syncthreads();
  if (t==0){
    float S  = w1[0]+w1[1]+w1[2]+w1[3];
    float S2 = w2[0]+w2[1]+w2[2]+w2[3];
    float m = S*(1.f/256.f);
    float v = S2*(1.f/256.f) - m*m;
    mean_s = m; rstd_s = rsqrtf(v + 1e-5f);
  }
  __syncthreads();
  out[(size_t)row*ldout + col0 + t] = (x-mean_s)*rstd_s*g[t] + bta[t];
}

// ---------------- MFMA bf16 GEMM: C = A(MxK) @ B(KxN) + bias; EPI 1 = silu; ACC adds into C
// 64x64 tile, 4 waves (16-row strip each), BK=32, reg-prefetch of next k-step.
// A-frag staging = flash Ks pattern (stride 40 u16); B-frag = flash Vt2 pair-packed (stride 20 u32).
template<int EPI, int ACC>
__global__ __launch_bounds__(256) void gemm_mfma_kernel(
    const float* __restrict__ A, int lda,
    const float* __restrict__ B, int ldb,
    const float* __restrict__ bias,
    float* __restrict__ C, int ldc, int col0,
    int M, int K)
{
  __shared__ __align__(16) unsigned short As[64*40];
  __shared__ __align__(16) unsigned Bst[64*20];
  const int t = threadIdx.x;
  const int w = t>>6, l = t&63, lr = l&15, lg = l>>4;
  const int m0 = blockIdx.x*64, n0 = blockIdx.y*64;

  const int ar = t>>2,  ak  = (t&3)<<3;   // A staging: row ar, k-base ak (8 wide)
  const int bc = t&63,  bk8 = (t>>6)<<3;  // B staging: col bc, k-base bk8 (8 wide)

  f32x4 acc[4];
  #pragma unroll
  for (int i=0;i<4;i++) acc[i]=(f32x4){0.f,0.f,0.f,0.f};

  float4 a0=make_float4(0,0,0,0), a1=make_float4(0,0,0,0);
  float bv[8];
  {
    if (m0+ar < M){
      const float4* p = reinterpret_cast<const float4*>(A + (size_t)(m0+ar)*lda + ak);
      a0 = p[0]; a1 = p[1];
    }
    #pragma unroll
    for (int j=0;j<8;j++) bv[j] = B[(size_t)(bk8+j)*ldb + n0 + bc];
  }

  const int NK = K>>5;
  for (int ks=0; ks<NK; ks++){
    __syncthreads();   // protect LDS from previous iteration's readers
    {
      float tmp[8] = {a0.x,a0.y,a0.z,a0.w,a1.x,a1.y,a1.z,a1.w};
      *reinterpret_cast<bf16x8*>(&As[ar*40 + ak]) = pack_bf8(tmp);
      unsigned pk[4];
      #pragma unroll
      for (int j=0;j<4;j++)
        pk[j] = (unsigned)bf16_rne(bv[2*j]) | ((unsigned)bf16_rne(bv[2*j+1])<<16);
      *reinterpret_cast<uint4*>(&Bst[bc*20 + (bk8>>1)]) = *reinterpret_cast<const uint4*>(pk);
    }
    __syncthreads();
    if (ks+1 < NK){
      int k0 = (ks+1)<<5;
      if (m0+ar < M){
        const float4* p = reinterpret_cast<const float4*>(A + (size_t)(m0+ar)*lda + k0 + ak);
        a0 = p[0]; a1 = p[1];
      }
      #pragma unroll
      for (int j=0;j<8;j++) bv[j] = B[(size_t)(k0+bk8+j)*ldb + n0 + bc];
    }
    bf16x8 af = *reinterpret_cast<const bf16x8*>(&As[(w*16+lr)*40 + lg*8]);
    #pragma unroll
    for (int cf=0; cf<4; cf++){
      bf16x8 bf = *reinterpret_cast<const bf16x8*>(&Bst[(cf*16+lr)*20 + lg*4]);
      acc[cf] = __builtin_amdgcn_mfma_f32_16x16x32_bf16(af, bf, acc[cf], 0,0,0);
    }
  }

  #pragma unroll
  for (int cf=0; cf<4; cf++){
    int col = n0 + cf*16 + lr;
    float bb = bias[col];
    #pragma unroll
    for (int r=0;r<4;r++){
      int row = m0 + w*16 + lg*4 + r;
      if (row >= M) continue;
      float v = acc[cf][r] + bb;
      if (ACC) v += C[(size_t)row*ldc + col0 + col];
      if (EPI==1) v = silu_f(v);
      C[(size_t)row*ldc + col0 + col] = v;
    }
  }
}

// ---------------- MFMA flash attention (unchanged, verified) ----------------
__global__ __launch_bounds__(256) void flash_mfma_kernel(
    const float* __restrict__ Qp, const float* __restrict__ Vp, const float* __restrict__ Ug,
    float* __restrict__ Out, int gateW)
{
  __shared__ __align__(16) unsigned short Ks[64*40];   // K tile bf16 [key][d], stride 40
  __shared__ __align__(16) unsigned Vt2[128*36];       // V^T pair-packed [dv][kp], stride 36 words
  __shared__ __align__(16) unsigned short Pb[4*16*72]; // per-wave P strip [q][key], stride 72

  const int t  = threadIdx.x;
  const int w  = t >> 6;
  const int l  = t & 63;
  const int lr = l & 15;
  const int lg = l >> 4;
  const int h  = blockIdx.y, b = blockIdx.z;
  const int r0 = blockIdx.x * 64;
  const float scale = 0.17677669529663687f;

  bf16x8 qf;
  {
    int n = r0 + w*16 + lr;
    float tmp[8];
    if (n < NTOK){
      const float4* q4 = reinterpret_cast<const float4*>(Qp + (size_t)(n*2+b)*256 + h*32 + lg*8);
      float4 a = q4[0], c = q4[1];
      tmp[0]=a.x; tmp[1]=a.y; tmp[2]=a.z; tmp[3]=a.w;
      tmp[4]=c.x; tmp[5]=c.y; tmp[6]=c.z; tmp[7]=c.w;
    } else {
      #pragma unroll
      for (int j=0;j<8;j++) tmp[j]=0.f;
    }
    #pragma unroll
    for (int j=0;j<8;j++) ((unsigned short*)&qf)[j] = bf16_rne(tmp[j]*scale);
  }

  f32x4 acc[8];
  #pragma unroll
  for (int i=0;i<8;i++) acc[i] = (f32x4){0.f,0.f,0.f,0.f};
  float mrun[4], lrun[4];
  #pragma unroll
  for (int r=0;r<4;r++){ mrun[r] = -1e30f; lrun[r] = 0.f; }

  const f32x4 zero4 = (f32x4){0.f,0.f,0.f,0.f};
  const int NT = (NTOK + 63)/64;

  for (int kt=0; kt<NT; kt++){
    const int k0 = kt*64;
    __syncthreads();

    {
      int key = t & 63, dh = t >> 6;
      int n = k0 + key;
      float tmp[8];
      if (n < NTOK){
        const float4* k4 = reinterpret_cast<const float4*>(Qp + (size_t)(n*2+b)*256 + h*32 + dh*8);
        float4 a = k4[0], c = k4[1];
        tmp[0]=a.x; tmp[1]=a.y; tmp[2]=a.z; tmp[3]=a.w;
        tmp[4]=c.x; tmp[5]=c.y; tmp[6]=c.z; tmp[7]=c.w;
      } else {
        #pragma unroll
        for (int j=0;j<8;j++) tmp[j]=0.f;
      }
      *reinterpret_cast<bf16x8*>(&Ks[key*40 + dh*8]) = pack_bf8(tmp);
    }

    {
      int kp = t & 31, dh = t >> 5;
      int n0 = k0 + kp*2, n1 = n0 + 1;
      const float* v0 = Vp + (size_t)(n0*2+b)*1024 + h*128 + dh*16;
      const float* v1 = Vp + (size_t)(n1*2+b)*1024 + h*128 + dh*16;
      float r0v[16], r1v[16];
      #pragma unroll
      for (int q=0;q<4;q++){
        float4 a = (n0<NTOK)? reinterpret_cast<const float4*>(v0)[q] : make_float4(0,0,0,0);
        float4 c = (n1<NTOK)? reinterpret_cast<const float4*>(v1)[q] : make_float4(0,0,0,0);
        r0v[q*4+0]=a.x; r0v[q*4+1]=a.y; r0v[q*4+2]=a.z; r0v[q*4+3]=a.w;
        r1v[q*4+0]=c.x; r1v[q*4+1]=c.y; r1v[q*4+2]=c.z; r1v[q*4+3]=c.w;
      }
      #pragma unroll
      for (int e=0;e<16;e++){
        unsigned pk = (unsigned)bf16_rne(r0v[e]) | ((unsigned)bf16_rne(r1v[e]) << 16);
        Vt2[(dh*16+e)*36 + kp] = pk;
      }
    }
    __syncthreads();

    f32x4 s[4];
    #pragma unroll
    for (int f=0;f<4;f++){
      bf16x8 kb = *reinterpret_cast<const bf16x8*>(&Ks[(16*f + lr)*40 + lg*8]);
      s[f] = __builtin_amdgcn_mfma_f32_16x16x32_bf16(qf, kb, zero4, 0, 0, 0);
    }
    if (k0 + 64 > NTOK){
      #pragma unroll
      for (int f=0;f<4;f++){
        if (k0 + 16*f + lr >= NTOK){ s[f][0]=-1e30f; s[f][1]=-1e30f; s[f][2]=-1e30f; s[f][3]=-1e30f; }
      }
    }

    float alpha[4];
    #pragma unroll
    for (int r=0;r<4;r++){
      float tm = fmaxf(fmaxf(s[0][r], s[1][r]), fmaxf(s[2][r], s[3][r]));
      #pragma unroll
      for (int off=1; off<16; off<<=1) tm = fmaxf(tm, __shfl_xor(tm, off));
      float mn = fmaxf(mrun[r], tm);
      alpha[r] = __expf(mrun[r] - mn);
      mrun[r] = mn;
      float ps = 0.f;
      #pragma unroll
      for (int f=0;f<4;f++){
        float p = __expf(s[f][r] - mn);
        s[f][r] = p; ps += p;
      }
      #pragma unroll
      for (int off=1; off<16; off<<=1) ps += __shfl_xor(ps, off);
      lrun[r] = lrun[r]*alpha[r] + ps;
    }

    unsigned short* pb = &Pb[w*16*72];
    #pragma unroll
    for (int f=0;f<4;f++)
      #pragma unroll
      for (int r=0;r<4;r++)
        pb[(lg*4+r)*72 + 16*f + lr] = bf16_rne(s[f][r]);
    bf16x8 pa0 = *reinterpret_cast<const bf16x8*>(&pb[lr*72 + 0*32 + lg*8]);
    bf16x8 pa1 = *reinterpret_cast<const bf16x8*>(&pb[lr*72 + 1*32 + lg*8]);

    #pragma unroll
    for (int i=0;i<8;i++){
      #pragma unroll
      for (int r=0;r<4;r++) acc[i][r] *= alpha[r];
    }
    #pragma unroll
    for (int c=0;c<8;c++){
      bf16x8 vb0 = *reinterpret_cast<const bf16x8*>(&Vt2[(c*16+lr)*36 + 0*16 + lg*4]);
      acc[c] = __builtin_amdgcn_mfma_f32_16x16x32_bf16(pa0, vb0, acc[c], 0, 0, 0);
    }
    #pragma unroll
    for (int c=0;c<8;c++){
      bf16x8 vb1 = *reinterpret_cast<const bf16x8*>(&Vt2[(c*16+lr)*36 + 1*16 + lg*4]);
      acc[c] = __builtin_amdgcn_mfma_f32_16x16x32_bf16(pa1, vb1, acc[c], 0, 0, 0);
    }
  }

  float linv[4];
  #pragma unroll
  for (int r=0;r<4;r++) linv[r] = 1.f / lrun[r];
  #pragma unroll
  for (int r=0;r<4;r++){
    int n = r0 + w*16 + lg*4 + r;
    if (n >= NTOK) continue;
    size_t rb = (size_t)(n*2+b);
    const float* ugr = Ug + rb*gateW;
    float* orow = Out + rb*1024 + h*128;
    #pragma unroll
    for (int c=0;c<8;c++){
      int dv = c*16 + lr;
      int ch = h*128 + dv;
      float v = acc[c][r]*linv[r];
      if (ch < gateW) v *= ugr[ch];
      orow[dv] = v;
    }
  }
}

// ---------------- local windowed attention (15x15), one block per (b,h,y)
// Phase A (scores+rel) via MFMA; phases B (softmax) and C (aggregation) as verified.
__global__ __launch_bounds__(256) void local_attn_kernel(
    const float* __restrict__ Qp, const float* __restrict__ Vp, const float* __restrict__ Ug,
    const float* __restrict__ Wrel, const float* __restrict__ brel_g, float* __restrict__ Out)
{
  __shared__ float sc[45][225];                 // 40.5 KB
  __shared__ __align__(16) float ubuf[7552];    // 30.2 KB union
  unsigned short* Qs = (unsigned short*)ubuf;   // [48][40] bf16 (scaled Q)
  unsigned short* Ks = Qs + 48*40;              // [48][40] bf16 (K row band)
  unsigned short* Ws = Ks + 48*40;              // [240][40] bf16 (Wrel_h)
  float* vsm = ubuf;                            // phase C: [59][128] f32

  const int t = threadIdx.x;
  const int w = t>>6, l = t&63;
  const int lr = l&15, lg = l>>4;
  const int y = blockIdx.x, h = blockIdx.y, b = blockIdx.z;
  const float scale = 0.17677669529663687f;
  const f32x4 zero4 = (f32x4){0.f,0.f,0.f,0.f};

  for (int i=t; i<45*225; i+=256) (&sc[0][0])[i] = -1e9f;

  for (int idx=t; idx<192; idx+=256){
    int row = idx>>2, c = (idx&3)<<3;
    float v[8];
    if (row < 45){
      const float4* p = reinterpret_cast<const float4*>(Qp + (size_t)((y*45+row)*2+b)*256 + h*32 + c);
      float4 a = p[0], d2 = p[1];
      v[0]=a.x*scale; v[1]=a.y*scale; v[2]=a.z*scale; v[3]=a.w*scale;
      v[4]=d2.x*scale; v[5]=d2.y*scale; v[6]=d2.z*scale; v[7]=d2.w*scale;
    } else {
      #pragma unroll
      for (int j=0;j<8;j++) v[j]=0.f;
    }
    *reinterpret_cast<bf16x8*>(&Qs[row*40 + c]) = pack_bf8(v);
  }
  for (int idx=t; idx<960; idx+=256){
    int row = idx>>2, c = (idx&3)<<3;
    float v[8];
    if (row < 225){
      const float4* p = reinterpret_cast<const float4*>(Wrel + ((size_t)h*225 + row)*32 + c);
      float4 a = p[0], d2 = p[1];
      v[0]=a.x; v[1]=a.y; v[2]=a.z; v[3]=a.w;
      v[4]=d2.x; v[5]=d2.y; v[6]=d2.z; v[7]=d2.w;
    } else {
      #pragma unroll
      for (int j=0;j<8;j++) v[j]=0.f;
    }
    *reinterpret_cast<bf16x8*>(&Ws[row*40 + c]) = pack_bf8(v);
  }
  __syncthreads();

  // R pass
  for (int fo=w; fo<15; fo+=4){
    bf16x8 wb = *reinterpret_cast<const bf16x8*>(&Ws[(16*fo+lr)*40 + lg*8]);
    int o = 16*fo + lr;
    int dyo = o/15, dxo = o - dyo*15;
    int yy = y + dyo - 7;
    bool ovalid = (o < 225) && (yy >= 0) && (yy < 45);
    float bb = ovalid ? brel_g[h*225+o] : 0.f;
    #pragma unroll
    for (int fa=0; fa<3; fa++){
      bf16x8 qa = *reinterpret_cast<const bf16x8*>(&Qs[(16*fa+lr)*40 + lg*8]);
      f32x4 rr = __builtin_amdgcn_mfma_f32_16x16x32_bf16(qa, wb, zero4, 0, 0, 0);
      if (ovalid){
        #pragma unroll
        for (int r=0;r<4;r++){
          int px = 16*fa + lg*4 + r;
          int xx = px + dxo - 7;
          if (px < 45 && xx >= 0 && xx < 45)
            sc[px][o] = rr[r] + bb;
        }
      }
    }
  }
  __syncthreads();

  // S pass
  for (int dy=0; dy<15; dy++){
    int yy = y + dy - 7;
    if (yy < 0 || yy >= 45) continue;
    __syncthreads();
    for (int idx=t; idx<192; idx+=256){
      int row = idx>>2, c = (idx&3)<<3;
      float v[8];
      if (row < 45){
        const float4* p = reinterpret_cast<const float4*>(Qp + (size_t)((yy*45+row)*2+b)*256 + h*32 + c);
        float4 a = p[0], d2 = p[1];
        v[0]=a.x; v[1]=a.y; v[2]=a.z; v[3]=a.w;
        v[4]=d2.x; v[5]=d2.y; v[6]=d2.z; v[7]=d2.w;
      } else {
        #pragma unroll
        for (int j=0;j<8;j++) v[j]=0.f;
      }
      *reinterpret_cast<bf16x8*>(&Ks[row*40 + c]) = pack_bf8(v);
    }
    __syncthreads();
    for (int pi=w; pi<7; pi+=4){
      int fa = (0x2110210u >> (4*pi)) & 7;
      int fb = (0x1201210u >> (4*pi)) & 7;
      bf16x8 qa = *reinterpret_cast<const bf16x8*>(&Qs[(16*fa+lr)*40 + lg*8]);
      bf16x8 kb = *reinterpret_cast<const bf16x8*>(&Ks[(16*fb+lr)*40 + lg*8]);
      f32x4 s = __builtin_amdgcn_mfma_f32_16x16x32_bf16(qa, kb, zero4, 0, 0, 0);
      int xx = 16*fb + lr;
      #pragma unroll
      for (int r=0;r<4;r++){
        int px = 16*fa + lg*4 + r;
        int dx = xx - px + 7;
        if (px < 45 && xx < 45 && dx >= 0 && dx < 15)
          sc[px][dy*15+dx] += s[r];
      }
    }
  }
  __syncthreads();

  // phase B softmax
  {
    int grp = t>>5, lane = t&31;
    for (int px = grp; px < 45; px += 8){
      float m = -1e30f;
      for (int o=lane; o<225; o+=32) m = fmaxf(m, sc[px][o]);
      #pragma unroll
      for (int off=16; off>0; off>>=1) m = fmaxf(m, __shfl_xor(m, off));
      float sum = 0.f;
      for (int o=lane; o<225; o+=32){ float p = __expf(sc[px][o]-m); sc[px][o]=p; sum += p; }
      #pragma unroll
      for (int off=16; off>0; off>>=1) sum += __shfl_xor(sum, off);
      float inv = 1.f/sum;
      for (int o=lane; o<225; o+=32) sc[px][o] *= inv;
    }
  }
  __syncthreads();

  // phase C aggregation
  float4 acc[6];
  #pragma unroll
  for (int i=0;i<6;i++) acc[i]=make_float4(0.f,0.f,0.f,0.f);
  for (int dy=0; dy<15; dy++){
    int yy = y + dy - 7;
    if (yy < 0 || yy >= 45) continue;
    __syncthreads();
    for (int idx=t; idx<59*32; idx+=256){
      int xxp = idx>>5, e4 = (idx&31)<<2;
      int xx = xxp - 7;
      float4 v = make_float4(0.f,0.f,0.f,0.f);
      if (xx>=0 && xx<45)
        v = *reinterpret_cast<const float4*>(Vp + (size_t)((yy*45+xx)*2+b)*1024 + h*128 + e4);
      *reinterpret_cast<float4*>(&vsm[xxp*128 + e4]) = v;
    }
    __syncthreads();
    #pragma unroll
    for (int k=0;k<6;k++){
      int slot = t + 256*k;
      if (slot >= 1440) break;
      int px = slot>>5, e4 = (slot&31)<<2;
      float4 a = acc[k];
      #pragma unroll
      for (int dx=0; dx<15; dx++){
        float p = sc[px][dy*15+dx];
        float4 v = *reinterpret_cast<const float4*>(&vsm[(px+dx)*128 + e4]);
        a.x += p*v.x; a.y += p*v.y; a.z += p*v.z; a.w += p*v.w;
      }
      acc[k] = a;
    }
  }

  #pragma unroll
  for (int k=0;k<6;k++){
    int slot = t + 256*k;
    if (slot >= 1440) break;
    int px = slot>>5, e4 = (slot&31)<<2;
    int n = y*45 + px;
    size_t rb = (size_t)(n*2+b);
    int ch = h*128 + e4;
    float4 a = acc[k];
    if (ch < 512){
      float4 g = *reinterpret_cast<const float4*>(Ug + rb*512 + ch);
      a.x *= g.x; a.y *= g.y; a.z *= g.z; a.w *= g.w;
    }
    *reinterpret_cast<float4*>(Out + rb*1024 + ch) = a;
  }
}

// ---------------- residual split
__global__ __launch_bounds__(256) void resid_split_kernel(
    const float* __restrict__ tgt, const float* __restrict__ t23,
    float* __restrict__ newt, float* __restrict__ tgtid)
{
  int idx = blockIdx.x*256 + threadIdx.x;
  if (idx >= NBS*256) return;
  int row = idx >> 8, c = idx & 255;
  newt[idx]  = tgt[idx] + t23[(size_t)row*512 + c];
  tgtid[idx] = t23[(size_t)row*512 + 256 + c];
}

// ---------------- final add
__global__ __launch_bounds__(256) void final_add_kernel(
    const float* __restrict__ newt, const float* __restrict__ tgtid,
    const float* __restrict__ s2, float* __restrict__ out)
{
  int idx = blockIdx.x*256 + threadIdx.x;
  if (idx >= NBS*256) return;
  int row = idx >> 8, c = idx & 255;
  out[idx]            = newt[idx]  + s2[(size_t)row*512 + c];
  out[NBS*256 + idx]  = tgtid[idx] + s2[(size_t)row*512 + 256 + c];
}

extern "C" void kernel_launch(void* const* d_in, const int* in_sizes, int n_in,
                              void* d_out, int out_size, void* d_ws, size_t ws_size,
                              hipStream_t stream)
{
  const float* tgt    = (const float*)d_in[0];
  const float* id_emb = (const float*)d_in[1];
  const float* ln1_g  = (const float*)d_in[2];
  const float* ln1_b  = (const float*)d_in[3];
  const float* W_qv   = (const float*)d_in[4];
  const float* b_qv   = (const float*)d_in[5];
  const float* W_u    = (const float*)d_in[6];
  const float* b_u    = (const float*)d_in[7];
  const float* W_idv  = (const float*)d_in[8];
  const float* b_idv  = (const float*)d_in[9];
  const float* lt_Wo  = (const float*)d_in[10];
  const float* lt_bo  = (const float*)d_in[11];
  const float* Wrel   = (const float*)d_in[12];
  const float* brel   = (const float*)d_in[13];
  const float* st_Wo  = (const float*)d_in[14];
  const float* st_bo  = (const float*)d_in[15];
  const float* ln2_g  = (const float*)d_in[16];
  const float* ln2_b  = (const float*)d_in[17];
  const float* idln2_g= (const float*)d_in[18];
  const float* idln2_b= (const float*)d_in[19];
  const float* sa_Wqk = (const float*)d_in[20];
  const float* sa_bqk = (const float*)d_in[21];
  const float* sa_Wv  = (const float*)d_in[22];
  const float* sa_bv  = (const float*)d_in[23];
  const float* sa_Wu  = (const float*)d_in[24];
  const float* sa_bu  = (const float*)d_in[25];
  const float* sa_Wo  = (const float*)d_in[26];
  const float* sa_bo  = (const float*)d_in[27];
  float* out = (float*)d_out;
  float* ws  = (float*)d_ws;

  float* tgt_ln = ws;                 // reused as newt
  float* Qbuf   = ws + 1036800;       // reused as Qs
  float* Vbuf   = ws + 2073600;       // reused as Vs
  float* Ubuf   = ws + 6220800;       // reused as s2
  float* G1     = ws + 8294400;
  float* G2     = ws + 12441600;      // reused as Us
  float* t23    = ws + 16588800;      // reused as x
  float* tgtid  = ws + 18662400;
  const int M = NBS;
  dim3 blk(256);
  int gx = (M+63)/64;   // 64

  ln256_kernel<<<M, 256, 0, stream>>>(tgt, ln1_g, ln1_b, tgt_ln, 256, 0);

  gemm_mfma_kernel<0,0><<<dim3(gx, 4), blk, 0, stream>>>(tgt_ln,256, W_qv,    768, b_qv,     Qbuf,256,  0,   M,256);
  gemm_mfma_kernel<1,0><<<dim3(gx, 8), blk, 0, stream>>>(tgt_ln,256, W_qv+256,768, b_qv+256, Vbuf,1024, 0,   M,256);
  gemm_mfma_kernel<1,0><<<dim3(gx, 8), blk, 0, stream>>>(tgt_ln,256, W_u,     512, b_u,      Ubuf,512,  0,   M,256);
  gemm_mfma_kernel<1,0><<<dim3(gx, 8), blk, 0, stream>>>(id_emb,256, W_idv,   512, b_idv,    Vbuf,1024, 512, M,256);

  flash_mfma_kernel<<<dim3(32,8,2), blk, 0, stream>>>(Qbuf, Vbuf, Ubuf, G1, 512);
  local_attn_kernel<<<dim3(45,8,2), blk, 0, stream>>>(Qbuf, Vbuf, Ubuf, Wrel, brel, G2);

  gemm_mfma_kernel<0,0><<<dim3(gx, 8), blk, 0, stream>>>(G1,1024, lt_Wo,512, lt_bo, t23,512,0, M,1024);
  gemm_mfma_kernel<0,1><<<dim3(gx, 8), blk, 0, stream>>>(G2,1024, st_Wo,512, st_bo, t23,512,0, M,1024);

  float* newt = tgt_ln;
  resid_split_kernel<<<(M*256+255)/256, blk, 0, stream>>>(tgt, t23, newt, tgtid);

  float* xbuf = t23;
  ln256_kernel<<<M, 256, 0, stream>>>(newt,  ln2_g,   ln2_b,   xbuf, 512, 0);
  ln256_kernel<<<M, 256, 0, stream>>>(tgtid, idln2_g, idln2_b, xbuf, 512, 256);

  float* Qs = Qbuf; float* Vs = Vbuf; float* Us = G2;
  gemm_mfma_kernel<0,0><<<dim3(gx, 4),  blk, 0, stream>>>(xbuf,512, sa_Wqk,256,  sa_bqk, Qs,256,  0, M,512);
  gemm_mfma_kernel<1,0><<<dim3(gx, 16), blk, 0, stream>>>(xbuf,512, sa_Wv,1024,  sa_bv,  Vs,1024, 0, M,512);
  gemm_mfma_kernel<1,0><<<dim3(gx, 16), blk, 0, stream>>>(xbuf,512, sa_Wu,1024,  sa_bu,  Us,1024, 0, M,512);

  flash_mfma_kernel<<<dim3(32,8,2), blk, 0, stream>>>(Qs, Vs, Us, G1, 1024);

  float* s2 = Ubuf;
  gemm_mfma_kernel<0,0><<<dim3(gx, 8), blk, 0, stream>>>(G1,1024, sa_Wo,512, sa_bo, s2,512,0, M,1024);

  final_add_kernel<<<(M*256+255)/256, blk, 0, stream>>>(newt, tgtid, s2, out);
}

// Round 6
// 616.205 us; speedup vs baseline: 5.4846x; 1.1765x over previous
//
#include <hip/hip_runtime.h>
#include <math.h>

#define NTOK 2025
#define NBS  4050   // NTOK * BS
#define BSZ  2

typedef __attribute__((ext_vector_type(8))) short bf16x8;
typedef __attribute__((ext_vector_type(4))) float f32x4;

__device__ __forceinline__ float silu_f(float v){ return v / (1.f + __expf(-v)); }

__device__ __forceinline__ unsigned short bf16_rne(float f){
  union { float f; unsigned u; } v; v.f = f;
  unsigned u = v.u;
  return (unsigned short)((u + 0x7FFFu + ((u >> 16) & 1u)) >> 16);
}

__device__ __forceinline__ bf16x8 pack_bf8(const float* v){
  bf16x8 r;
  #pragma unroll
  for (int j=0;j<8;j++) ((unsigned short*)&r)[j] = bf16_rne(v[j]);
  return r;
}

// ---------------- LayerNorm over C=256 ----------------
__global__ __launch_bounds__(256) void ln256_kernel(
    const float* __restrict__ in, const float* __restrict__ g,
    const float* __restrict__ bta, float* __restrict__ out,
    int ldout, int col0)
{
  int row = blockIdx.x;
  int t = threadIdx.x;
  float x = in[(size_t)row*256 + t];
  float s = x, s2 = x*x;
  #pragma unroll
  for (int o=32; o>0; o>>=1){ s += __shfl_xor(s,o); s2 += __shfl_xor(s2,o); }
  __shared__ float w1[4], w2[4];
  __shared__ float mean_s, rstd_s;
  int wid = t>>6, lane = t&63;
  if (lane==0){ w1[wid]=s; w2[wid]=s2; }
  __syncthreads();
  if (t==0){
    float S  = w1[0]+w1[1]+w1[2]+w1[3];
    float S2 = w2[0]+w2[1]+w2[2]+w2[3];
    float m = S*(1.f/256.f);
    float v = S2*(1.f/256.f) - m*m;
    mean_s = m; rstd_s = rsqrtf(v + 1e-5f);
  }
  __syncthreads();
  out[(size_t)row*ldout + col0 + t] = (x-mean_s)*rstd_s*g[t] + bta[t];
}

// ---------------- MFMA bf16 GEMM (unchanged, verified) ----------------
template<int EPI, int ACC>
__global__ __launch_bounds__(256) void gemm_mfma_kernel(
    const float* __restrict__ A, int lda,
    const float* __restrict__ B, int ldb,
    const float* __restrict__ bias,
    float* __restrict__ C, int ldc, int col0,
    int M, int K)
{
  __shared__ __align__(16) unsigned short As[64*40];
  __shared__ __align__(16) unsigned Bst[64*20];
  const int t = threadIdx.x;
  const int w = t>>6, l = t&63, lr = l&15, lg = l>>4;
  const int m0 = blockIdx.x*64, n0 = blockIdx.y*64;

  const int ar = t>>2,  ak  = (t&3)<<3;
  const int bc = t&63,  bk8 = (t>>6)<<3;

  f32x4 acc[4];
  #pragma unroll
  for (int i=0;i<4;i++) acc[i]=(f32x4){0.f,0.f,0.f,0.f};

  float4 a0=make_float4(0,0,0,0), a1=make_float4(0,0,0,0);
  float bv[8];
  {
    if (m0+ar < M){
      const float4* p = reinterpret_cast<const float4*>(A + (size_t)(m0+ar)*lda + ak);
      a0 = p[0]; a1 = p[1];
    }
    #pragma unroll
    for (int j=0;j<8;j++) bv[j] = B[(size_t)(bk8+j)*ldb + n0 + bc];
  }

  const int NK = K>>5;
  for (int ks=0; ks<NK; ks++){
    __syncthreads();
    {
      float tmp[8] = {a0.x,a0.y,a0.z,a0.w,a1.x,a1.y,a1.z,a1.w};
      *reinterpret_cast<bf16x8*>(&As[ar*40 + ak]) = pack_bf8(tmp);
      unsigned pk[4];
      #pragma unroll
      for (int j=0;j<4;j++)
        pk[j] = (unsigned)bf16_rne(bv[2*j]) | ((unsigned)bf16_rne(bv[2*j+1])<<16);
      *reinterpret_cast<uint4*>(&Bst[bc*20 + (bk8>>1)]) = *reinterpret_cast<const uint4*>(pk);
    }
    __syncthreads();
    if (ks+1 < NK){
      int k0 = (ks+1)<<5;
      if (m0+ar < M){
        const float4* p = reinterpret_cast<const float4*>(A + (size_t)(m0+ar)*lda + k0 + ak);
        a0 = p[0]; a1 = p[1];
      }
      #pragma unroll
      for (int j=0;j<8;j++) bv[j] = B[(size_t)(k0+bk8+j)*ldb + n0 + bc];
    }
    bf16x8 af = *reinterpret_cast<const bf16x8*>(&As[(w*16+lr)*40 + lg*8]);
    #pragma unroll
    for (int cf=0; cf<4; cf++){
      bf16x8 bf = *reinterpret_cast<const bf16x8*>(&Bst[(cf*16+lr)*20 + lg*4]);
      acc[cf] = __builtin_amdgcn_mfma_f32_16x16x32_bf16(af, bf, acc[cf], 0,0,0);
    }
  }

  #pragma unroll
  for (int cf=0; cf<4; cf++){
    int col = n0 + cf*16 + lr;
    float bb = bias[col];
    #pragma unroll
    for (int r=0;r<4;r++){
      int row = m0 + w*16 + lg*4 + r;
      if (row >= M) continue;
      float v = acc[cf][r] + bb;
      if (ACC) v += C[(size_t)row*ldc + col0 + col];
      if (EPI==1) v = silu_f(v);
      C[(size_t)row*ldc + col0 + col] = v;
    }
  }
}

// ---------------- MFMA flash attention (unchanged, verified) ----------------
__global__ __launch_bounds__(256) void flash_mfma_kernel(
    const float* __restrict__ Qp, const float* __restrict__ Vp, const float* __restrict__ Ug,
    float* __restrict__ Out, int gateW)
{
  __shared__ __align__(16) unsigned short Ks[64*40];
  __shared__ __align__(16) unsigned Vt2[128*36];
  __shared__ __align__(16) unsigned short Pb[4*16*72];

  const int t  = threadIdx.x;
  const int w  = t >> 6;
  const int l  = t & 63;
  const int lr = l & 15;
  const int lg = l >> 4;
  const int h  = blockIdx.y, b = blockIdx.z;
  const int r0 = blockIdx.x * 64;
  const float scale = 0.17677669529663687f;

  bf16x8 qf;
  {
    int n = r0 + w*16 + lr;
    float tmp[8];
    if (n < NTOK){
      const float4* q4 = reinterpret_cast<const float4*>(Qp + (size_t)(n*2+b)*256 + h*32 + lg*8);
      float4 a = q4[0], c = q4[1];
      tmp[0]=a.x; tmp[1]=a.y; tmp[2]=a.z; tmp[3]=a.w;
      tmp[4]=c.x; tmp[5]=c.y; tmp[6]=c.z; tmp[7]=c.w;
    } else {
      #pragma unroll
      for (int j=0;j<8;j++) tmp[j]=0.f;
    }
    #pragma unroll
    for (int j=0;j<8;j++) ((unsigned short*)&qf)[j] = bf16_rne(tmp[j]*scale);
  }

  f32x4 acc[8];
  #pragma unroll
  for (int i=0;i<8;i++) acc[i] = (f32x4){0.f,0.f,0.f,0.f};
  float mrun[4], lrun[4];
  #pragma unroll
  for (int r=0;r<4;r++){ mrun[r] = -1e30f; lrun[r] = 0.f; }

  const f32x4 zero4 = (f32x4){0.f,0.f,0.f,0.f};
  const int NT = (NTOK + 63)/64;

  for (int kt=0; kt<NT; kt++){
    const int k0 = kt*64;
    __syncthreads();

    {
      int key = t & 63, dh = t >> 6;
      int n = k0 + key;
      float tmp[8];
      if (n < NTOK){
        const float4* k4 = reinterpret_cast<const float4*>(Qp + (size_t)(n*2+b)*256 + h*32 + dh*8);
        float4 a = k4[0], c = k4[1];
        tmp[0]=a.x; tmp[1]=a.y; tmp[2]=a.z; tmp[3]=a.w;
        tmp[4]=c.x; tmp[5]=c.y; tmp[6]=c.z; tmp[7]=c.w;
      } else {
        #pragma unroll
        for (int j=0;j<8;j++) tmp[j]=0.f;
      }
      *reinterpret_cast<bf16x8*>(&Ks[key*40 + dh*8]) = pack_bf8(tmp);
    }

    {
      int kp = t & 31, dh = t >> 5;
      int n0 = k0 + kp*2, n1 = n0 + 1;
      const float* v0 = Vp + (size_t)(n0*2+b)*1024 + h*128 + dh*16;
      const float* v1 = Vp + (size_t)(n1*2+b)*1024 + h*128 + dh*16;
      float r0v[16], r1v[16];
      #pragma unroll
      for (int q=0;q<4;q++){
        float4 a = (n0<NTOK)? reinterpret_cast<const float4*>(v0)[q] : make_float4(0,0,0,0);
        float4 c = (n1<NTOK)? reinterpret_cast<const float4*>(v1)[q] : make_float4(0,0,0,0);
        r0v[q*4+0]=a.x; r0v[q*4+1]=a.y; r0v[q*4+2]=a.z; r0v[q*4+3]=a.w;
        r1v[q*4+0]=c.x; r1v[q*4+1]=c.y; r1v[q*4+2]=c.z; r1v[q*4+3]=c.w;
      }
      #pragma unroll
      for (int e=0;e<16;e++){
        unsigned pk = (unsigned)bf16_rne(r0v[e]) | ((unsigned)bf16_rne(r1v[e]) << 16);
        Vt2[(dh*16+e)*36 + kp] = pk;
      }
    }
    __syncthreads();

    f32x4 s[4];
    #pragma unroll
    for (int f=0;f<4;f++){
      bf16x8 kb = *reinterpret_cast<const bf16x8*>(&Ks[(16*f + lr)*40 + lg*8]);
      s[f] = __builtin_amdgcn_mfma_f32_16x16x32_bf16(qf, kb, zero4, 0, 0, 0);
    }
    if (k0 + 64 > NTOK){
      #pragma unroll
      for (int f=0;f<4;f++){
        if (k0 + 16*f + lr >= NTOK){ s[f][0]=-1e30f; s[f][1]=-1e30f; s[f][2]=-1e30f; s[f][3]=-1e30f; }
      }
    }

    float alpha[4];
    #pragma unroll
    for (int r=0;r<4;r++){
      float tm = fmaxf(fmaxf(s[0][r], s[1][r]), fmaxf(s[2][r], s[3][r]));
      #pragma unroll
      for (int off=1; off<16; off<<=1) tm = fmaxf(tm, __shfl_xor(tm, off));
      float mn = fmaxf(mrun[r], tm);
      alpha[r] = __expf(mrun[r] - mn);
      mrun[r] = mn;
      float ps = 0.f;
      #pragma unroll
      for (int f=0;f<4;f++){
        float p = __expf(s[f][r] - mn);
        s[f][r] = p; ps += p;
      }
      #pragma unroll
      for (int off=1; off<16; off<<=1) ps += __shfl_xor(ps, off);
      lrun[r] = lrun[r]*alpha[r] + ps;
    }

    unsigned short* pb = &Pb[w*16*72];
    #pragma unroll
    for (int f=0;f<4;f++)
      #pragma unroll
      for (int r=0;r<4;r++)
        pb[(lg*4+r)*72 + 16*f + lr] = bf16_rne(s[f][r]);
    bf16x8 pa0 = *reinterpret_cast<const bf16x8*>(&pb[lr*72 + 0*32 + lg*8]);
    bf16x8 pa1 = *reinterpret_cast<const bf16x8*>(&pb[lr*72 + 1*32 + lg*8]);

    #pragma unroll
    for (int i=0;i<8;i++){
      #pragma unroll
      for (int r=0;r<4;r++) acc[i][r] *= alpha[r];
    }
    #pragma unroll
    for (int c=0;c<8;c++){
      bf16x8 vb0 = *reinterpret_cast<const bf16x8*>(&Vt2[(c*16+lr)*36 + 0*16 + lg*4]);
      acc[c] = __builtin_amdgcn_mfma_f32_16x16x32_bf16(pa0, vb0, acc[c], 0, 0, 0);
    }
    #pragma unroll
    for (int c=0;c<8;c++){
      bf16x8 vb1 = *reinterpret_cast<const bf16x8*>(&Vt2[(c*16+lr)*36 + 1*16 + lg*4]);
      acc[c] = __builtin_amdgcn_mfma_f32_16x16x32_bf16(pa1, vb1, acc[c], 0, 0, 0);
    }
  }

  float linv[4];
  #pragma unroll
  for (int r=0;r<4;r++) linv[r] = 1.f / lrun[r];
  #pragma unroll
  for (int r=0;r<4;r++){
    int n = r0 + w*16 + lg*4 + r;
    if (n >= NTOK) continue;
    size_t rb = (size_t)(n*2+b);
    const float* ugr = Ug + rb*gateW;
    float* orow = Out + rb*1024 + h*128;
    #pragma unroll
    for (int c=0;c<8;c++){
      int dv = c*16 + lr;
      int ch = h*128 + dv;
      float v = acc[c][r]*linv[r];
      if (ch < gateW) v *= ugr[ch];
      orow[dv] = v;
    }
  }
}

// ---------------- local windowed attention v3: all-MFMA, fewer barriers ----------------
// One block per (y,h,b). Phases: R (Q@Wrel^T), S (banded Q@K^T, 6-dy chunks),
// softmax, C (per-dy banded P~ @ V^ via MFMA). LDS 67.4KB -> 2 blocks/CU.
__global__ __launch_bounds__(256) void local_attn_kernel(
    const float* __restrict__ Qp, const float* __restrict__ Vp, const float* __restrict__ Ug,
    const float* __restrict__ Wrel, const float* __restrict__ brel_g, float* __restrict__ Out)
{
  __shared__ float sc[45][225];               // 40.5 KB
  __shared__ __align__(16) float ubuf[6720];  // 26.9 KB union
  unsigned short* Qs = (unsigned short*)ubuf; // [48*40] bf16 scaled Q
  unsigned short* Wk = Qs + 48*40;            // phase R: Ws[240*40]; phase S: Kc[6*48*40]
  unsigned short* Abuf = (unsigned short*)ubuf;      // phase C: P~ [48 rows][72 stride]
  unsigned*       Vt2  = (unsigned*)(ubuf + 1728);   // phase C: V^ pair-packed [128][36]

  const int t = threadIdx.x;
  const int w = t>>6, l = t&63;
  const int lr = l&15, lg = l>>4;
  const int y = blockIdx.x, h = blockIdx.y, b = blockIdx.z;
  const float scale = 0.17677669529663687f;
  const f32x4 zero4 = (f32x4){0.f,0.f,0.f,0.f};

  for (int i=t; i<45*225; i+=256) (&sc[0][0])[i] = -1e9f;

  // stage Qs (scaled) + Ws
  for (int idx=t; idx<192; idx+=256){
    int row = idx>>2, c = (idx&3)<<3;
    float v[8];
    if (row < 45){
      const float4* p = reinterpret_cast<const float4*>(Qp + (size_t)((y*45+row)*2+b)*256 + h*32 + c);
      float4 a = p[0], d2 = p[1];
      v[0]=a.x*scale; v[1]=a.y*scale; v[2]=a.z*scale; v[3]=a.w*scale;
      v[4]=d2.x*scale; v[5]=d2.y*scale; v[6]=d2.z*scale; v[7]=d2.w*scale;
    } else {
      #pragma unroll
      for (int j=0;j<8;j++) v[j]=0.f;
    }
    *reinterpret_cast<bf16x8*>(&Qs[row*40 + c]) = pack_bf8(v);
  }
  for (int idx=t; idx<960; idx+=256){
    int row = idx>>2, c = (idx&3)<<3;
    float v[8];
    if (row < 225){
      const float4* p = reinterpret_cast<const float4*>(Wrel + ((size_t)h*225 + row)*32 + c);
      float4 a = p[0], d2 = p[1];
      v[0]=a.x; v[1]=a.y; v[2]=a.z; v[3]=a.w;
      v[4]=d2.x; v[5]=d2.y; v[6]=d2.z; v[7]=d2.w;
    } else {
      #pragma unroll
      for (int j=0;j<8;j++) v[j]=0.f;
    }
    *reinterpret_cast<bf16x8*>(&Wk[row*40 + c]) = pack_bf8(v);
  }
  __syncthreads();

  // ---- R pass: R[px][o] = q[px]·wrel[o]; write R+brel at valid slots ----
  for (int fo=w; fo<15; fo+=4){
    bf16x8 wb = *reinterpret_cast<const bf16x8*>(&Wk[(16*fo+lr)*40 + lg*8]);
    int o = 16*fo + lr;
    int dyo = o/15, dxo = o - dyo*15;
    int yyo = y + dyo - 7;
    bool ovalid = (o < 225) && (yyo >= 0) && (yyo < 45);
    float bb = ovalid ? brel_g[h*225+o] : 0.f;
    #pragma unroll
    for (int fa=0; fa<3; fa++){
      bf16x8 qa = *reinterpret_cast<const bf16x8*>(&Qs[(16*fa+lr)*40 + lg*8]);
      f32x4 rr = __builtin_amdgcn_mfma_f32_16x16x32_bf16(qa, wb, zero4, 0, 0, 0);
      if (ovalid){
        #pragma unroll
        for (int r=0;r<4;r++){
          int px = 16*fa + lg*4 + r;
          int xx = px + dxo - 7;
          if (px < 45 && xx >= 0 && xx < 45)
            sc[px][o] = rr[r] + bb;
        }
      }
    }
  }

  // ---- S pass: 3 chunks of up to 6 dy ----
  for (int c0=0; c0<15; c0+=6){
    int nc = (15-c0 < 6) ? (15-c0) : 6;
    __syncthreads();   // Wk free (R done / prev chunk compute done)
    for (int idx=t; idx<nc*192; idx+=256){
      int d = idx/192, r192 = idx - d*192;
      int row = r192>>2, c = (r192&3)<<3;
      int yy = y + c0 + d - 7;
      if (yy < 0 || yy >= 45) continue;
      float v[8];
      if (row < 45){
        const float4* p = reinterpret_cast<const float4*>(Qp + (size_t)((yy*45+row)*2+b)*256 + h*32 + c);
        float4 a = p[0], d2 = p[1];
        v[0]=a.x; v[1]=a.y; v[2]=a.z; v[3]=a.w;
        v[4]=d2.x; v[5]=d2.y; v[6]=d2.z; v[7]=d2.w;
      } else {
        #pragma unroll
        for (int j=0;j<8;j++) v[j]=0.f;
      }
      *reinterpret_cast<bf16x8*>(&Wk[d*1920 + row*40 + c]) = pack_bf8(v);
    }
    __syncthreads();
    for (int u=w; u<nc*7; u+=4){
      int d = u/7, pi = u - d*7;
      int dy = c0 + d, yy = y + dy - 7;
      if (yy < 0 || yy >= 45) continue;
      int fa = (0x2110210u >> (4*pi)) & 7;
      int fb = (0x1201210u >> (4*pi)) & 7;
      bf16x8 qa = *reinterpret_cast<const bf16x8*>(&Qs[(16*fa+lr)*40 + lg*8]);
      bf16x8 kb = *reinterpret_cast<const bf16x8*>(&Wk[d*1920 + (16*fb+lr)*40 + lg*8]);
      f32x4 s = __builtin_amdgcn_mfma_f32_16x16x32_bf16(qa, kb, zero4, 0, 0, 0);
      int xx = 16*fb + lr;
      #pragma unroll
      for (int r=0;r<4;r++){
        int px = 16*fa + lg*4 + r;
        int dx = xx - px + 7;
        if (px < 45 && xx < 45 && dx >= 0 && dx < 15)
          sc[px][dy*15+dx] += s[r];
      }
    }
  }
  __syncthreads();

  // ---- softmax (wave-parallel, unchanged) ----
  {
    int grp = t>>5, lane = t&31;
    for (int px = grp; px < 45; px += 8){
      float m = -1e30f;
      for (int o=lane; o<225; o+=32) m = fmaxf(m, sc[px][o]);
      #pragma unroll
      for (int off=16; off>0; off>>=1) m = fmaxf(m, __shfl_xor(m, off));
      float sum = 0.f;
      for (int o=lane; o<225; o+=32){ float p = __expf(sc[px][o]-m); sc[px][o]=p; sum += p; }
      #pragma unroll
      for (int off=16; off>0; off>>=1) sum += __shfl_xor(sum, off);
      float inv = 1.f/sum;
      for (int o=lane; o<225; o+=32) sc[px][o] *= inv;
    }
  }

  // ---- phase C: per-dy MFMA aggregation: acc += P~ (48x64) @ V^ (64x128) ----
  f32x4 acc[6];
  #pragma unroll
  for (int i=0;i<6;i++) acc[i]=(f32x4){0.f,0.f,0.f,0.f};

  for (int dy=0; dy<15; dy++){
    int yy = y + dy - 7;
    if (yy < 0 || yy >= 45) continue;   // block-uniform; masked p==0 anyway
    __syncthreads();                    // previous compute done; A/Vt2 free (also covers softmax on 1st iter)

    // build P~ : A[px][kk] = (0<=kk-px<15 && 0<=kk-7<45) ? p : 0 ; dense pair-packed write
    {
      unsigned* A32 = (unsigned*)Abuf;
      for (int i=t; i<48*32; i+=256){
        int px = i>>5, wd = i&31;
        int kk0 = wd*2, kk1 = kk0+1;
        float p0 = 0.f, p1 = 0.f;
        if (px < 45){
          int dx0 = kk0 - px, dx1 = kk1 - px;
          if (dx0 >= 0 && dx0 < 15 && kk0 >= 7 && kk0 < 52) p0 = sc[px][dy*15+dx0];
          if (dx1 >= 0 && dx1 < 15 && kk1 >= 7 && kk1 < 52) p1 = sc[px][dy*15+dx1];
        }
        A32[px*36 + wd] = (unsigned)bf16_rne(p0) | ((unsigned)bf16_rne(p1)<<16);
      }
    }
    // stage V^ transposed pair-packed: key kk -> xx = kk-7
    {
      int kp = t&31, dh = t>>5;
      int xx0 = kp*2 - 7, xx1 = xx0 + 1;
      const float* v0p = Vp + ((size_t)((yy*45+xx0)*2+b))*1024 + h*128 + dh*16;
      const float* v1p = Vp + ((size_t)((yy*45+xx1)*2+b))*1024 + h*128 + dh*16;
      bool ok0 = (xx0 >= 0 && xx0 < 45), ok1 = (xx1 >= 0 && xx1 < 45);
      float r0v[16], r1v[16];
      #pragma unroll
      for (int q=0;q<4;q++){
        float4 a = ok0 ? reinterpret_cast<const float4*>(v0p)[q] : make_float4(0,0,0,0);
        float4 c = ok1 ? reinterpret_cast<const float4*>(v1p)[q] : make_float4(0,0,0,0);
        r0v[q*4+0]=a.x; r0v[q*4+1]=a.y; r0v[q*4+2]=a.z; r0v[q*4+3]=a.w;
        r1v[q*4+0]=c.x; r1v[q*4+1]=c.y; r1v[q*4+2]=c.z; r1v[q*4+3]=c.w;
      }
      #pragma unroll
      for (int e=0;e<16;e++){
        unsigned pk = (unsigned)bf16_rne(r0v[e]) | ((unsigned)bf16_rne(r1v[e]) << 16);
        Vt2[(dh*16+e)*36 + kp] = pk;
      }
    }
    __syncthreads();

    // compute: 24 (fa,ef) units over 4 waves, 2 k-steps each
    for (int u=w; u<24; u+=4){
      int fa = u>>3, ef = u&7, ua = (u-w)>>2;
      bf16x8 a0 = *reinterpret_cast<const bf16x8*>(&Abuf[(16*fa+lr)*72 + 0*32 + lg*8]);
      bf16x8 b0 = *reinterpret_cast<const bf16x8*>(&Vt2[(ef*16+lr)*36 + 0*16 + lg*4]);
      acc[ua] = __builtin_amdgcn_mfma_f32_16x16x32_bf16(a0, b0, acc[ua], 0,0,0);
      bf16x8 a1 = *reinterpret_cast<const bf16x8*>(&Abuf[(16*fa+lr)*72 + 1*32 + lg*8]);
      bf16x8 b1 = *reinterpret_cast<const bf16x8*>(&Vt2[(ef*16+lr)*36 + 1*16 + lg*4]);
      acc[ua] = __builtin_amdgcn_mfma_f32_16x16x32_bf16(a1, b1, acc[ua], 0,0,0);
    }
  }

  // ---- epilogue: gate + store ----
  for (int u=w; u<24; u+=4){
    int fa = u>>3, ef = u&7, ua = (u-w)>>2;
    #pragma unroll
    for (int r=0;r<4;r++){
      int px = 16*fa + lg*4 + r;
      if (px >= 45) continue;
      int e = ef*16 + lr;
      int n = y*45 + px;
      size_t rb = (size_t)(n*2+b);
      int ch = h*128 + e;
      float v = acc[ua][r];
      if (ch < 512) v *= Ug[rb*512 + ch];
      Out[rb*1024 + ch] = v;
    }
  }
}

// ---------------- residual split
__global__ __launch_bounds__(256) void resid_split_kernel(
    const float* __restrict__ tgt, const float* __restrict__ t23,
    float* __restrict__ newt, float* __restrict__ tgtid)
{
  int idx = blockIdx.x*256 + threadIdx.x;
  if (idx >= NBS*256) return;
  int row = idx >> 8, c = idx & 255;
  newt[idx]  = tgt[idx] + t23[(size_t)row*512 + c];
  tgtid[idx] = t23[(size_t)row*512 + 256 + c];
}

// ---------------- final add
__global__ __launch_bounds__(256) void final_add_kernel(
    const float* __restrict__ newt, const float* __restrict__ tgtid,
    const float* __restrict__ s2, float* __restrict__ out)
{
  int idx = blockIdx.x*256 + threadIdx.x;
  if (idx >= NBS*256) return;
  int row = idx >> 8, c = idx & 255;
  out[idx]            = newt[idx]  + s2[(size_t)row*512 + c];
  out[NBS*256 + idx]  = tgtid[idx] + s2[(size_t)row*512 + 256 + c];
}

extern "C" void kernel_launch(void* const* d_in, const int* in_sizes, int n_in,
                              void* d_out, int out_size, void* d_ws, size_t ws_size,
                              hipStream_t stream)
{
  const float* tgt    = (const float*)d_in[0];
  const float* id_emb = (const float*)d_in[1];
  const float* ln1_g  = (const float*)d_in[2];
  const float* ln1_b  = (const float*)d_in[3];
  const float* W_qv   = (const float*)d_in[4];
  const float* b_qv   = (const float*)d_in[5];
  const float* W_u    = (const float*)d_in[6];
  const float* b_u    = (const float*)d_in[7];
  const float* W_idv  = (const float*)d_in[8];
  const float* b_idv  = (const float*)d_in[9];
  const float* lt_Wo  = (const float*)d_in[10];
  const float* lt_bo  = (const float*)d_in[11];
  const float* Wrel   = (const float*)d_in[12];
  const float* brel   = (const float*)d_in[13];
  const float* st_Wo  = (const float*)d_in[14];
  const float* st_bo  = (const float*)d_in[15];
  const float* ln2_g  = (const float*)d_in[16];
  const float* ln2_b  = (const float*)d_in[17];
  const float* idln2_g= (const float*)d_in[18];
  const float* idln2_b= (const float*)d_in[19];
  const float* sa_Wqk = (const float*)d_in[20];
  const float* sa_bqk = (const float*)d_in[21];
  const float* sa_Wv  = (const float*)d_in[22];
  const float* sa_bv  = (const float*)d_in[23];
  const float* sa_Wu  = (const float*)d_in[24];
  const float* sa_bu  = (const float*)d_in[25];
  const float* sa_Wo  = (const float*)d_in[26];
  const float* sa_bo  = (const float*)d_in[27];
  float* out = (float*)d_out;
  float* ws  = (float*)d_ws;

  float* tgt_ln = ws;                 // reused as newt
  float* Qbuf   = ws + 1036800;       // reused as Qs
  float* Vbuf   = ws + 2073600;       // reused as Vs
  float* Ubuf   = ws + 6220800;       // reused as s2
  float* G1     = ws + 8294400;
  float* G2     = ws + 12441600;      // reused as Us
  float* t23    = ws + 16588800;      // reused as x
  float* tgtid  = ws + 18662400;
  const int M = NBS;
  dim3 blk(256);
  int gx = (M+63)/64;   // 64

  ln256_kernel<<<M, 256, 0, stream>>>(tgt, ln1_g, ln1_b, tgt_ln, 256, 0);

  gemm_mfma_kernel<0,0><<<dim3(gx, 4), blk, 0, stream>>>(tgt_ln,256, W_qv,    768, b_qv,     Qbuf,256,  0,   M,256);
  gemm_mfma_kernel<1,0><<<dim3(gx, 8), blk, 0, stream>>>(tgt_ln,256, W_qv+256,768, b_qv+256, Vbuf,1024, 0,   M,256);
  gemm_mfma_kernel<1,0><<<dim3(gx, 8), blk, 0, stream>>>(tgt_ln,256, W_u,     512, b_u,      Ubuf,512,  0,   M,256);
  gemm_mfma_kernel<1,0><<<dim3(gx, 8), blk, 0, stream>>>(id_emb,256, W_idv,   512, b_idv,    Vbuf,1024, 512, M,256);

  flash_mfma_kernel<<<dim3(32,8,2), blk, 0, stream>>>(Qbuf, Vbuf, Ubuf, G1, 512);
  local_attn_kernel<<<dim3(45,8,2), blk, 0, stream>>>(Qbuf, Vbuf, Ubuf, Wrel, brel, G2);

  gemm_mfma_kernel<0,0><<<dim3(gx, 8), blk, 0, stream>>>(G1,1024, lt_Wo,512, lt_bo, t23,512,0, M,1024);
  gemm_mfma_kernel<0,1><<<dim3(gx, 8), blk, 0, stream>>>(G2,1024, st_Wo,512, st_bo, t23,512,0, M,1024);

  float* newt = tgt_ln;
  resid_split_kernel<<<(M*256+255)/256, blk, 0, stream>>>(tgt, t23, newt, tgtid);

  float* xbuf = t23;
  ln256_kernel<<<M, 256, 0, stream>>>(newt,  ln2_g,   ln2_b,   xbuf, 512, 0);
  ln256_kernel<<<M, 256, 0, stream>>>(tgtid, idln2_g, idln2_b, xbuf, 512, 256);

  float* Qs = Qbuf; float* Vs = Vbuf; float* Us = G2;
  gemm_mfma_kernel<0,0><<<dim3(gx, 4),  blk, 0, stream>>>(xbuf,512, sa_Wqk,256,  sa_bqk, Qs,256,  0, M,512);
  gemm_mfma_kernel<1,0><<<dim3(gx, 16), blk, 0, stream>>>(xbuf,512, sa_Wv,1024,  sa_bv,  Vs,1024, 0, M,512);
  gemm_mfma_kernel<1,0><<<dim3(gx, 16), blk, 0, stream>>>(xbuf,512, sa_Wu,1024,  sa_bu,  Us,1024, 0, M,512);

  flash_mfma_kernel<<<dim3(32,8,2), blk, 0, stream>>>(Qs, Vs, Us, G1, 1024);

  float* s2 = Ubuf;
  gemm_mfma_kernel<0,0><<<dim3(gx, 8), blk, 0, stream>>>(G1,1024, sa_Wo,512, sa_bo, s2,512,0, M,1024);

  final_add_kernel<<<(M*256+255)/256, blk, 0, stream>>>(newt, tgtid, s2, out);
}